// Round 7
// baseline (125.763 us; speedup 1.0000x reference)
//
// R7: fuse context into the K/V GEMM (k_kvctx): MFMA kv tiles -> exp/dump to
//     swizzled LDS -> per-head 32x32 context partials, no kb/vb buffers.
//     q-GEMM split into k_qgemm (unchanged math). Rest same as R6.
#include <hip/hip_runtime.h>
#include <hip/hip_bf16.h>
#include <math.h>

#define B 16
#define C 256
#define H 4
#define D 32
#define HID 128
#define O3 384
#define N 4096
#define NSPLIT 32
#define QSCALE 0.17677669529663687f  // 1/sqrt(32)
#define RMS_MUL 16.0f                // sqrt(256)
#define EPS 1e-12f

typedef __attribute__((ext_vector_type(8))) short short8;
typedef __attribute__((ext_vector_type(4))) float f32x4;

__device__ __forceinline__ ushort f2bf(float f) {
  __hip_bfloat16 h = __float2bfloat16(f);
  return *(ushort*)&h;
}
__device__ __forceinline__ float bf2f(ushort u) {
  unsigned int v = ((unsigned int)u) << 16;
  return *(float*)&v;
}
__device__ __forceinline__ void load_lds16(const void* g, void* l) {
  __builtin_amdgcn_global_load_lds((const __attribute__((address_space(1))) void*)g,
                                   (__attribute__((address_space(3))) void*)l, 16, 0, 0);
}

// ---- weight prep: wA[o][c] = bf16(wqkv[o][c]*g[c]) ----
__global__ __launch_bounds__(256) void k_prep_w(const float* __restrict__ wqkv,
                                                const float* __restrict__ g,
                                                ushort* __restrict__ wA) {
  int idx = blockIdx.x * 256 + threadIdx.x;
  wA[idx] = f2bf(wqkv[idx] * g[idx & (C - 1)]);
}

// ---- x prep: rmsnorm + transpose to xbf[b][n][c] (bf16, c contiguous) ----
__global__ __launch_bounds__(256) void k_prep_x(const float* __restrict__ x,
                                                ushort* __restrict__ xbf) {
  __shared__ ushort xl[C][64];
  __shared__ float red[4][64];
  __shared__ float invs[64];
  int t = threadIdx.x, w4 = t >> 6, ln = t & 63;
  int b = blockIdx.y, n0 = blockIdx.x * 64;
  const float* xb = x + (size_t)b * C * N + n0;
  float ss = 0.f;
  #pragma unroll
  for (int it = 0; it < 64; ++it) {
    int c = it * 4 + w4;
    float v = xb[(size_t)c * N + ln];
    ss += v * v;
    xl[c][ln] = f2bf(v);
  }
  red[w4][ln] = ss;
  __syncthreads();
  if (t < 64) {
    float tot = red[0][t] + red[1][t] + red[2][t] + red[3][t];
    invs[t] = RMS_MUL / fmaxf(sqrtf(tot), EPS);
  }
  __syncthreads();
  float inv = invs[ln];
  ushort* dst = xbf + ((size_t)(b * N + n0 + ln)) * C + w4 * 64;
  #pragma unroll
  for (int ch = 0; ch < 8; ++ch) {
    union { ushort s[8]; uint4 v; } u;
    #pragma unroll
    for (int j = 0; j < 8; ++j)
      u.s[j] = f2bf(bf2f(xl[w4 * 64 + ch * 8 + j][ln]) * inv);
    *(uint4*)(dst + ch * 8) = u.v;
  }
}

// ---- q GEMM (512 blocks): q rows only, softmax fused, transposed qT write ----
__global__ __launch_bounds__(256) void k_qgemm(const ushort* __restrict__ A,
                                               const ushort* __restrict__ Bm,
                                               ushort* __restrict__ qT) {
  const int K = 256;
  __shared__ ushort Abuf[128 * 64];
  __shared__ ushort Bbuf[128 * 64];
  int bid = blockIdx.x;
  int work = (bid & 7) * 64 + (bid >> 3);
  int xt = work & 31, b = work >> 5;
  int t = threadIdx.x;
  int lane = t & 63, w = t >> 6;
  int wr = w >> 1, wc = w & 1;
  int n0 = xt * 128;
  const ushort* Bb = Bm + ((size_t)b * N + n0) * K;
  f32x4 acc[4][4] = {};
  for (int k0 = 0; k0 < K; k0 += 64) {
    #pragma unroll
    for (int i = 0; i < 4; ++i) {
      int chunk = w * 4 + i;
      int row = chunk * 8 + (lane >> 3);
      int col = k0 + (lane & 7) * 8;
      load_lds16(A + (size_t)row * K + col, Abuf + chunk * 512);
      load_lds16(Bb + (size_t)row * K + col, Bbuf + chunk * 512);
    }
    __syncthreads();
    #pragma unroll
    for (int kk = 0; kk < 2; ++kk) {
      short8 af[4], bfr[4];
      #pragma unroll
      for (int m = 0; m < 4; ++m)
        af[m] = *(const short8*)&Abuf[(wr * 64 + m * 16 + (lane & 15)) * 64 + kk * 32 + (lane >> 4) * 8];
      #pragma unroll
      for (int nn = 0; nn < 4; ++nn)
        bfr[nn] = *(const short8*)&Bbuf[(wc * 64 + nn * 16 + (lane & 15)) * 64 + kk * 32 + (lane >> 4) * 8];
      #pragma unroll
      for (int m = 0; m < 4; ++m)
        #pragma unroll
        for (int nn = 0; nn < 4; ++nn)
          acc[m][nn] = __builtin_amdgcn_mfma_f32_16x16x32_bf16(af[m], bfr[nn], acc[m][nn], 0, 0, 0);
    }
    __syncthreads();
  }
  // q-softmax over d=32 groups, per column, in-register
  #pragma unroll
  for (int hh = 0; hh < 2; ++hh) {
    #pragma unroll
    for (int nn = 0; nn < 4; ++nn) {
      int m0 = hh * 2;
      float pm = -1e30f;
      #pragma unroll
      for (int mi = 0; mi < 2; ++mi)
        #pragma unroll
        for (int j = 0; j < 4; ++j) pm = fmaxf(pm, acc[m0 + mi][nn][j]);
      pm = fmaxf(pm, __shfl_xor(pm, 16));
      pm = fmaxf(pm, __shfl_xor(pm, 32));
      float e[2][4], ps = 0.f;
      #pragma unroll
      for (int mi = 0; mi < 2; ++mi)
        #pragma unroll
        for (int j = 0; j < 4; ++j) {
          e[mi][j] = __expf(acc[m0 + mi][nn][j] - pm);
          ps += e[mi][j];
        }
      ps += __shfl_xor(ps, 16);
      ps += __shfl_xor(ps, 32);
      float rs = QSCALE / ps;
      #pragma unroll
      for (int mi = 0; mi < 2; ++mi)
        #pragma unroll
        for (int j = 0; j < 4; ++j) acc[m0 + mi][nn][j] = e[mi][j] * rs;
    }
  }
  ushort* qTb = qT + ((size_t)(b * N + n0)) * HID;
  #pragma unroll
  for (int m = 0; m < 4; ++m)
    #pragma unroll
    for (int nn = 0; nn < 4; ++nn) {
      int dd = wr * 64 + m * 16 + (lane >> 4) * 4;
      int n = wc * 64 + nn * 16 + (lane & 15);
      union { ushort s[4]; uint2 v; } u;
      #pragma unroll
      for (int j = 0; j < 4; ++j) u.s[j] = f2bf(acc[m][nn][j]);
      *(uint2*)&qTb[(size_t)n * HID + dd] = u.v;
    }
}

// ---- K/V GEMM + fused context (512 blocks = 32 slabs x 16 b) ----
// A = wA + 128*256 (k rows 0..127, v rows 128..255). Tile M=256 x N=128, K=256.
// Epilogue: dump exp(k)/v as bf16 to swizzled LDS [n][row^((n&7)<<2)], then
// per-head (wave=head) 32x32 context partials + k-row sums -> ctxp.
__global__ __launch_bounds__(256) void k_kvctx(const ushort* __restrict__ A,
                                               const ushort* __restrict__ Bm,
                                               float* __restrict__ ctxp) {
  const int K = 256;
  __shared__ ushort lds[32768];              // 64 KB: staging then kvt[128][256]
  ushort* Abuf = lds;                        // 256x64
  ushort* Bbuf = lds + 16384;                // 128x64
  int bid = blockIdx.x;
  int work = (bid & 7) * 64 + (bid >> 3);
  int s = work & 31, b = work >> 5;
  int t = threadIdx.x;
  int lane = t & 63, w = t >> 6;
  int n0 = s * 128;
  const ushort* Bb = Bm + ((size_t)b * N + n0) * K;
  f32x4 acc[4][8] = {};
  for (int k0 = 0; k0 < K; k0 += 64) {
    #pragma unroll
    for (int i = 0; i < 8; ++i) {
      int chunk = w * 8 + i;                 // 0..31, rows 0..255
      int row = chunk * 8 + (lane >> 3);
      int col = k0 + (lane & 7) * 8;
      load_lds16(A + (size_t)row * K + col, Abuf + chunk * 512);
    }
    #pragma unroll
    for (int i = 0; i < 4; ++i) {
      int chunk = w * 4 + i;                 // 0..15, rows 0..127
      int row = chunk * 8 + (lane >> 3);
      int col = k0 + (lane & 7) * 8;
      load_lds16(Bb + (size_t)row * K + col, Bbuf + chunk * 512);
    }
    __syncthreads();
    #pragma unroll
    for (int kk = 0; kk < 2; ++kk) {
      short8 af[4], bfr[8];
      #pragma unroll
      for (int m = 0; m < 4; ++m)
        af[m] = *(const short8*)&Abuf[(w * 64 + m * 16 + (lane & 15)) * 64 + kk * 32 + (lane >> 4) * 8];
      #pragma unroll
      for (int nn = 0; nn < 8; ++nn)
        bfr[nn] = *(const short8*)&Bbuf[(nn * 16 + (lane & 15)) * 64 + kk * 32 + (lane >> 4) * 8];
      #pragma unroll
      for (int m = 0; m < 4; ++m)
        #pragma unroll
        for (int nn = 0; nn < 8; ++nn)
          acc[m][nn] = __builtin_amdgcn_mfma_f32_16x16x32_bf16(af[m], bfr[nn], acc[m][nn], 0, 0, 0);
    }
    __syncthreads();
  }
  // ---- dump to kvt[n][256] with XOR swizzle; k rows get exp() ----
  bool isk = (w < 2);                        // wave-uniform
  #pragma unroll
  for (int m = 0; m < 4; ++m)
    #pragma unroll
    for (int nn = 0; nn < 8; ++nn) {
      int row0 = w * 64 + m * 16 + (lane >> 4) * 4;   // 0..255 (0..127=k, 128..255=v)
      int n = nn * 16 + (lane & 15);
      union { ushort us[4]; uint2 v; } u;
      #pragma unroll
      for (int j = 0; j < 4; ++j) {
        float val = acc[m][nn][j];
        if (isk) val = __expf(val);
        u.us[j] = f2bf(val);
      }
      *(uint2*)&lds[n * 256 + (row0 ^ ((n & 7) << 2))] = u.v;
    }
  __syncthreads();
  // ---- per-head context: wave w = head h ----
  int h = w;
  int d0 = (lane >> 3) * 4;                  // 0..28
  int e0 = (lane & 7) * 4;                   // 0..28
  float cacc[4][4] = {};
  float ks[4] = {0.f, 0.f, 0.f, 0.f};
  for (int nn = 0; nn < 128; ++nn) {
    int xr = (nn & 7) << 2;
    union { ushort us[4]; uint2 v; } ku, vu;
    ku.v = *(const uint2*)&lds[nn * 256 + ((h * D + d0) ^ xr)];
    vu.v = *(const uint2*)&lds[nn * 256 + ((128 + h * D + e0) ^ xr)];
    float kf[4], vf[4];
    #pragma unroll
    for (int i = 0; i < 4; ++i) { kf[i] = bf2f(ku.us[i]); vf[i] = bf2f(vu.us[i]); }
    #pragma unroll
    for (int i = 0; i < 4; ++i) {
      ks[i] += kf[i];
      #pragma unroll
      for (int j = 0; j < 4; ++j) cacc[i][j] += kf[i] * vf[j];
    }
  }
  float* cb = ctxp + (size_t)(s * 64 + (b * 4 + h)) * 1056;
  #pragma unroll
  for (int i = 0; i < 4; ++i) {
    f32x4 v = {cacc[i][0], cacc[i][1], cacc[i][2], cacc[i][3]};
    *(f32x4*)(cb + (d0 + i) * 32 + e0) = v;
  }
  if ((lane & 7) == 0) {
    #pragma unroll
    for (int i = 0; i < 4; ++i) cb[1024 + d0 + i] = ks[i];
  }
}

// ---- reduce partials + normalize + Weff[b][o][h*32+d] = sum_e wout[o][h*32+e]*ctx[d][e] ----
__global__ __launch_bounds__(256) void k_redweff(const float* __restrict__ ctxp,
                                                 const float* __restrict__ wout,
                                                 ushort* __restrict__ Weff) {
  __shared__ float ctxn[D][D + 1];
  __shared__ float ksum[D];
  int bh = blockIdx.x;
  int b = bh >> 2, h = bh & 3;
  int t = threadIdx.x;
  int d = t >> 3, e0 = (t & 7) * 4;
  float vs[4] = {0.f, 0.f, 0.f, 0.f};
  float ks = 0.f;
  for (int s = 0; s < NSPLIT; ++s) {
    const float* cb = ctxp + (size_t)(s * 64 + bh) * 1056;
    f32x4 v = *(const f32x4*)(cb + d * 32 + e0);
    vs[0] += v[0]; vs[1] += v[1]; vs[2] += v[2]; vs[3] += v[3];
    if (t < 32) ks += cb[1024 + t];
  }
  if (t < 32) ksum[t] = ks;
  __syncthreads();
  float rk = 1.f / ksum[d];
  #pragma unroll
  for (int j = 0; j < 4; ++j) ctxn[d][e0 + j] = vs[j] * rk;
  __syncthreads();
  float wrow[D];
  #pragma unroll
  for (int e = 0; e < D; ++e) wrow[e] = wout[t * HID + h * D + e];
  ushort* wb = Weff + ((size_t)(b * C + t)) * HID + h * D;
  #pragma unroll
  for (int g = 0; g < 4; ++g) {
    union { ushort s[8]; uint4 v; } u;
    #pragma unroll
    for (int dj = 0; dj < 8; ++dj) {
      int dd = g * 8 + dj;
      float a = 0.f;
      #pragma unroll
      for (int e = 0; e < D; ++e) a += wrow[e] * ctxn[dd][e];
      u.s[dj] = f2bf(a);
    }
    *(uint4*)(wb + g * 8) = u.v;
  }
}

// ---- GEMM2 (1024 blocks, XCD-swizzled): out[b] = Weff[b] x qT + bias, fused rmsnorm ----
__global__ __launch_bounds__(256) void k_gemm2(const ushort* __restrict__ WeffG,
                                               const ushort* __restrict__ Bm,
                                               const float* __restrict__ bias,
                                               const float* __restrict__ g,
                                               float* __restrict__ outp) {
  const int K = HID;
  __shared__ ushort Abuf[256 * 64];
  __shared__ ushort Bbuf[64 * 64];
  __shared__ float ssred[4][64];
  __shared__ float biasl[C], gl[C];
  int bid = blockIdx.x;
  int work = (bid & 7) * 128 + (bid >> 3);
  int nt = work & 63, b = work >> 6;
  int t = threadIdx.x;
  int lane = t & 63, w = t >> 6;
  int n0 = nt * 64;
  biasl[t] = bias[t];
  gl[t] = g[t];
  const ushort* A = WeffG + (size_t)b * C * K;
  const ushort* Bb = Bm + ((size_t)b * N + n0) * K;
  f32x4 acc[4][4] = {};
  for (int k0 = 0; k0 < K; k0 += 64) {
    #pragma unroll
    for (int i = 0; i < 8; ++i) {
      int chunk = w * 8 + i;
      int row = chunk * 8 + (lane >> 3);
      int col = k0 + (lane & 7) * 8;
      load_lds16(A + (size_t)row * K + col, Abuf + chunk * 512);
    }
    #pragma unroll
    for (int i = 0; i < 2; ++i) {
      int chunk = w * 2 + i;
      int row = chunk * 8 + (lane >> 3);
      int col = k0 + (lane & 7) * 8;
      load_lds16(Bb + (size_t)row * K + col, Bbuf + chunk * 512);
    }
    __syncthreads();
    #pragma unroll
    for (int kk = 0; kk < 2; ++kk) {
      short8 af[4], bfr[4];
      #pragma unroll
      for (int m = 0; m < 4; ++m)
        af[m] = *(const short8*)&Abuf[(w * 64 + m * 16 + (lane & 15)) * 64 + kk * 32 + (lane >> 4) * 8];
      #pragma unroll
      for (int nn = 0; nn < 4; ++nn)
        bfr[nn] = *(const short8*)&Bbuf[(nn * 16 + (lane & 15)) * 64 + kk * 32 + (lane >> 4) * 8];
      #pragma unroll
      for (int m = 0; m < 4; ++m)
        #pragma unroll
        for (int nn = 0; nn < 4; ++nn)
          acc[m][nn] = __builtin_amdgcn_mfma_f32_16x16x32_bf16(af[m], bfr[nn], acc[m][nn], 0, 0, 0);
    }
    __syncthreads();
  }
  #pragma unroll
  for (int m = 0; m < 4; ++m)
    #pragma unroll
    for (int j = 0; j < 4; ++j) {
      int row = w * 64 + m * 16 + (lane >> 4) * 4 + j;
      float bv = biasl[row];
      #pragma unroll
      for (int nn = 0; nn < 4; ++nn) acc[m][nn][j] += bv;
    }
  float ssp[4];
  #pragma unroll
  for (int nn = 0; nn < 4; ++nn) {
    float s = 0.f;
    #pragma unroll
    for (int m = 0; m < 4; ++m)
      #pragma unroll
      for (int j = 0; j < 4; ++j) s += acc[m][nn][j] * acc[m][nn][j];
    s += __shfl_xor(s, 16);
    s += __shfl_xor(s, 32);
    ssp[nn] = s;
  }
  if ((lane >> 4) == 0) {
    #pragma unroll
    for (int nn = 0; nn < 4; ++nn) ssred[w][nn * 16 + (lane & 15)] = ssp[nn];
  }
  __syncthreads();
  float inv[4];
  #pragma unroll
  for (int nn = 0; nn < 4; ++nn) {
    int col = nn * 16 + (lane & 15);
    float tot = ssred[0][col] + ssred[1][col] + ssred[2][col] + ssred[3][col];
    inv[nn] = RMS_MUL / fmaxf(sqrtf(tot), EPS);
  }
  float* Cb = outp + (size_t)b * C * N + n0;
  #pragma unroll
  for (int m = 0; m < 4; ++m)
    #pragma unroll
    for (int j = 0; j < 4; ++j) {
      int row = w * 64 + m * 16 + (lane >> 4) * 4 + j;
      float gm = gl[row];
      #pragma unroll
      for (int nn = 0; nn < 4; ++nn) {
        int col = nn * 16 + (lane & 15);
        Cb[(size_t)row * N + col] = acc[m][nn][j] * inv[nn] * gm;
      }
    }
}

extern "C" void kernel_launch(void* const* d_in, const int* in_sizes, int n_in,
                              void* d_out, int out_size, void* d_ws, size_t ws_size,
                              hipStream_t stream) {
  const float* x    = (const float*)d_in[0];
  const float* gn   = (const float*)d_in[1];
  const float* wqkv = (const float*)d_in[2];
  const float* wout = (const float*)d_in[3];
  const float* bout = (const float*)d_in[4];
  const float* gout = (const float*)d_in[5];
  float* out = (float*)d_out;
  float* ws  = (float*)d_ws;

  ushort* xbf  = (ushort*)ws;                    // 32 MB [b][n][c]
  ushort* qT   = (ushort*)(ws + 8388608);        // 16 MB [b][n][d]
  float*  ctxp = ws + 12582912;                  // 8.65 MB
  ushort* Weff = (ushort*)(ws + 14745600);       // 1 MB
  ushort* wA   = (ushort*)(ws + 15007744);       // 192 KB
  // total ~60.5 MB

  k_prep_w <<<384, 256, 0, stream>>>(wqkv, gn, wA);
  k_prep_x <<<dim3(64, 16), 256, 0, stream>>>(x, xbf);
  k_qgemm  <<<512, 256, 0, stream>>>(wA, xbf, qT);
  k_kvctx  <<<512, 256, 0, stream>>>(wA + 128 * 256, xbf, ctxp);
  k_redweff<<<64, 256, 0, stream>>>(ctxp, wout, Weff);
  k_gemm2  <<<1024, 256, 0, stream>>>(Weff, qT, bout, gout, out);
}

// Round 8
// 112.791 us; speedup vs baseline: 1.1150x; 1.1150x over previous
//
// R8: k_kvctx epilogue via MFMA (LDS-swizzled exp(k)/v dump -> 16 MFMA/wave ctx)
//     replacing the serial VALU loop; k_qgemm qT write via LDS transpose ->
//     coalesced 16B stores. Rest same as R7.
#include <hip/hip_runtime.h>
#include <hip/hip_bf16.h>
#include <math.h>

#define B 16
#define C 256
#define H 4
#define D 32
#define HID 128
#define O3 384
#define N 4096
#define NSPLIT 32
#define QSCALE 0.17677669529663687f  // 1/sqrt(32)
#define RMS_MUL 16.0f                // sqrt(256)
#define EPS 1e-12f

typedef __attribute__((ext_vector_type(8))) short short8;
typedef __attribute__((ext_vector_type(4))) float f32x4;

__device__ __forceinline__ ushort f2bf(float f) {
  __hip_bfloat16 h = __float2bfloat16(f);
  return *(ushort*)&h;
}
__device__ __forceinline__ float bf2f(ushort u) {
  unsigned int v = ((unsigned int)u) << 16;
  return *(float*)&v;
}
__device__ __forceinline__ void load_lds16(const void* g, void* l) {
  __builtin_amdgcn_global_load_lds((const __attribute__((address_space(1))) void*)g,
                                   (__attribute__((address_space(3))) void*)l, 16, 0, 0);
}

// ---- weight prep: wA[o][c] = bf16(wqkv[o][c]*g[c]) ----
__global__ __launch_bounds__(256) void k_prep_w(const float* __restrict__ wqkv,
                                                const float* __restrict__ g,
                                                ushort* __restrict__ wA) {
  int idx = blockIdx.x * 256 + threadIdx.x;
  wA[idx] = f2bf(wqkv[idx] * g[idx & (C - 1)]);
}

// ---- x prep: rmsnorm + transpose to xbf[b][n][c] (bf16, c contiguous) ----
__global__ __launch_bounds__(256) void k_prep_x(const float* __restrict__ x,
                                                ushort* __restrict__ xbf) {
  __shared__ ushort xl[C][64];
  __shared__ float red[4][64];
  __shared__ float invs[64];
  int t = threadIdx.x, w4 = t >> 6, ln = t & 63;
  int b = blockIdx.y, n0 = blockIdx.x * 64;
  const float* xb = x + (size_t)b * C * N + n0;
  float ss = 0.f;
  #pragma unroll
  for (int it = 0; it < 64; ++it) {
    int c = it * 4 + w4;
    float v = xb[(size_t)c * N + ln];
    ss += v * v;
    xl[c][ln] = f2bf(v);
  }
  red[w4][ln] = ss;
  __syncthreads();
  if (t < 64) {
    float tot = red[0][t] + red[1][t] + red[2][t] + red[3][t];
    invs[t] = RMS_MUL / fmaxf(sqrtf(tot), EPS);
  }
  __syncthreads();
  float inv = invs[ln];
  ushort* dst = xbf + ((size_t)(b * N + n0 + ln)) * C + w4 * 64;
  #pragma unroll
  for (int ch = 0; ch < 8; ++ch) {
    union { ushort s[8]; uint4 v; } u;
    #pragma unroll
    for (int j = 0; j < 8; ++j)
      u.s[j] = f2bf(bf2f(xl[w4 * 64 + ch * 8 + j][ln]) * inv);
    *(uint4*)(dst + ch * 8) = u.v;
  }
}

// ---- q GEMM (512 blocks): softmax fused; qT written via LDS transpose ----
__global__ __launch_bounds__(256) void k_qgemm(const ushort* __restrict__ A,
                                               const ushort* __restrict__ Bm,
                                               ushort* __restrict__ qT) {
  const int K = 256;
  __shared__ ushort sh[16384];               // 32 KB: staging, then q[n][d] dump
  ushort* Abuf = sh;
  ushort* Bbuf = sh + 8192;
  int bid = blockIdx.x;
  int work = (bid & 7) * 64 + (bid >> 3);
  int xt = work & 31, b = work >> 5;
  int t = threadIdx.x;
  int lane = t & 63, w = t >> 6;
  int wr = w >> 1, wc = w & 1;
  int n0 = xt * 128;
  const ushort* Bb = Bm + ((size_t)b * N + n0) * K;
  f32x4 acc[4][4] = {};
  for (int k0 = 0; k0 < K; k0 += 64) {
    #pragma unroll
    for (int i = 0; i < 4; ++i) {
      int chunk = w * 4 + i;
      int row = chunk * 8 + (lane >> 3);
      int col = k0 + (lane & 7) * 8;
      load_lds16(A + (size_t)row * K + col, Abuf + chunk * 512);
      load_lds16(Bb + (size_t)row * K + col, Bbuf + chunk * 512);
    }
    __syncthreads();
    #pragma unroll
    for (int kk = 0; kk < 2; ++kk) {
      short8 af[4], bfr[4];
      #pragma unroll
      for (int m = 0; m < 4; ++m)
        af[m] = *(const short8*)&Abuf[(wr * 64 + m * 16 + (lane & 15)) * 64 + kk * 32 + (lane >> 4) * 8];
      #pragma unroll
      for (int nn = 0; nn < 4; ++nn)
        bfr[nn] = *(const short8*)&Bbuf[(wc * 64 + nn * 16 + (lane & 15)) * 64 + kk * 32 + (lane >> 4) * 8];
      #pragma unroll
      for (int m = 0; m < 4; ++m)
        #pragma unroll
        for (int nn = 0; nn < 4; ++nn)
          acc[m][nn] = __builtin_amdgcn_mfma_f32_16x16x32_bf16(af[m], bfr[nn], acc[m][nn], 0, 0, 0);
    }
    __syncthreads();
  }
  // q-softmax over d=32 groups, per column, in-register
  #pragma unroll
  for (int hh = 0; hh < 2; ++hh) {
    #pragma unroll
    for (int nn = 0; nn < 4; ++nn) {
      int m0 = hh * 2;
      float pm = -1e30f;
      #pragma unroll
      for (int mi = 0; mi < 2; ++mi)
        #pragma unroll
        for (int j = 0; j < 4; ++j) pm = fmaxf(pm, acc[m0 + mi][nn][j]);
      pm = fmaxf(pm, __shfl_xor(pm, 16));
      pm = fmaxf(pm, __shfl_xor(pm, 32));
      float e[2][4], ps = 0.f;
      #pragma unroll
      for (int mi = 0; mi < 2; ++mi)
        #pragma unroll
        for (int j = 0; j < 4; ++j) {
          e[mi][j] = __expf(acc[m0 + mi][nn][j] - pm);
          ps += e[mi][j];
        }
      ps += __shfl_xor(ps, 16);
      ps += __shfl_xor(ps, 32);
      float rs = QSCALE / ps;
      #pragma unroll
      for (int mi = 0; mi < 2; ++mi)
        #pragma unroll
        for (int j = 0; j < 4; ++j) acc[m0 + mi][nn][j] = e[mi][j] * rs;
    }
  }
  // dump to sh[n][d] (swizzled), then coalesced qT write
  #pragma unroll
  for (int m = 0; m < 4; ++m)
    #pragma unroll
    for (int nn = 0; nn < 4; ++nn) {
      int d0 = wr * 64 + m * 16 + (lane >> 4) * 4;
      int n = wc * 64 + nn * 16 + (lane & 15);
      union { ushort us[4]; uint2 v; } u;
      #pragma unroll
      for (int j = 0; j < 4; ++j) u.us[j] = f2bf(acc[m][nn][j]);
      *(uint2*)&sh[(n * 128 + d0) ^ ((n & 7) << 3)] = u.v;
    }
  __syncthreads();
  ushort* qTb = qT + ((size_t)(b * N + n0)) * HID;
  #pragma unroll
  for (int p = 0; p < 8; ++p) {
    int flat = p * 256 + t;
    int n = flat >> 4;
    int d0 = (flat & 15) * 8;
    uint4 v = *(const uint4*)&sh[(n * 128 + d0) ^ ((n & 7) << 3)];
    *(uint4*)&qTb[(size_t)n * HID + d0] = v;
  }
}

// ---- K/V GEMM + fused context via MFMA epilogue (512 blocks) ----
// A = wA + 128*256 (rows 0..127 = k, 128..255 = v). Tile M=256 x N=128, K=256.
__global__ __launch_bounds__(256) void k_kvctx(const ushort* __restrict__ A,
                                               const ushort* __restrict__ Bm,
                                               float* __restrict__ ctxp) {
  const int K = 256;
  __shared__ ushort lds[32768];              // 64 KB: staging, then kvt[256][128]
  ushort* Abuf = lds;                        // 256x64 (16384)
  ushort* Bbuf = lds + 16384;                // 128x64 (8192)
  int bid = blockIdx.x;
  int work = (bid & 7) * 64 + (bid >> 3);
  int sl = work & 31, b = work >> 5;
  int t = threadIdx.x;
  int lane = t & 63, w = t >> 6;
  int n0 = sl * 128;
  const ushort* Bb = Bm + ((size_t)b * N + n0) * K;
  f32x4 acc[4][8] = {};
  for (int k0 = 0; k0 < K; k0 += 64) {
    #pragma unroll
    for (int i = 0; i < 8; ++i) {
      int chunk = w * 8 + i;                 // rows 0..255
      int row = chunk * 8 + (lane >> 3);
      int col = k0 + (lane & 7) * 8;
      load_lds16(A + (size_t)row * K + col, Abuf + chunk * 512);
    }
    #pragma unroll
    for (int i = 0; i < 4; ++i) {
      int chunk = w * 4 + i;                 // rows 0..127
      int row = chunk * 8 + (lane >> 3);
      int col = k0 + (lane & 7) * 8;
      load_lds16(Bb + (size_t)row * K + col, Bbuf + chunk * 512);
    }
    __syncthreads();
    #pragma unroll
    for (int kk = 0; kk < 2; ++kk) {
      short8 af[4], bfr[8];
      #pragma unroll
      for (int m = 0; m < 4; ++m)
        af[m] = *(const short8*)&Abuf[(w * 64 + m * 16 + (lane & 15)) * 64 + kk * 32 + (lane >> 4) * 8];
      #pragma unroll
      for (int nn = 0; nn < 8; ++nn)
        bfr[nn] = *(const short8*)&Bbuf[(nn * 16 + (lane & 15)) * 64 + kk * 32 + (lane >> 4) * 8];
      #pragma unroll
      for (int m = 0; m < 4; ++m)
        #pragma unroll
        for (int nn = 0; nn < 8; ++nn)
          acc[m][nn] = __builtin_amdgcn_mfma_f32_16x16x32_bf16(af[m], bfr[nn], acc[m][nn], 0, 0, 0);
    }
    __syncthreads();
  }
  float* cbb = ctxp + (size_t)(sl * 64 + b * 4) * 1056;   // + h*1056 later
  // ---- k waves: exp in-register, ksum via shuffles ----
  if (w < 2) {
    #pragma unroll
    for (int m = 0; m < 4; ++m)
      #pragma unroll
      for (int nn = 0; nn < 8; ++nn)
        #pragma unroll
        for (int j = 0; j < 4; ++j) acc[m][nn][j] = __expf(acc[m][nn][j]);
    #pragma unroll
    for (int m = 0; m < 4; ++m)
      #pragma unroll
      for (int j = 0; j < 4; ++j) {
        float s = 0.f;
        #pragma unroll
        for (int nn = 0; nn < 8; ++nn) s += acc[m][nn][j];
        s += __shfl_xor(s, 1); s += __shfl_xor(s, 2);
        s += __shfl_xor(s, 4); s += __shfl_xor(s, 8);
        if ((lane & 15) == 0) {
          int r = w * 64 + m * 16 + (lane >> 4) * 4 + j;   // 0..127
          cbb[(size_t)(r >> 5) * 1056 + 1024 + (r & 31)] = s;
        }
      }
  }
  // ---- dump bf16 to kvt[row][n], swizzle idx ^= (row&7)<<3 (16B granular) ----
  #pragma unroll
  for (int m = 0; m < 4; ++m)
    #pragma unroll
    for (int nn = 0; nn < 8; ++nn) {
      int r0 = w * 64 + m * 16 + (lane >> 4) * 4;
      int n = nn * 16 + (lane & 15);
      #pragma unroll
      for (int j = 0; j < 4; ++j) {
        int r = r0 + j;
        lds[(r * 128 + n) ^ ((r & 7) << 3)] = f2bf(acc[m][nn][j]);
      }
    }
  __syncthreads();
  // ---- ctx via MFMA: wave w = head h; M=32(d) x N=32(e) x K=128(n) ----
  int h = w;
  f32x4 cacc[2][2] = {};
  #pragma unroll
  for (int kk = 0; kk < 4; ++kk) {
    short8 af2[2], bf2v[2];
    #pragma unroll
    for (int m = 0; m < 2; ++m) {
      int r = h * D + m * 16 + (lane & 15);
      af2[m] = *(const short8*)&lds[(r * 128 + kk * 32 + (lane >> 4) * 8) ^ ((r & 7) << 3)];
    }
    #pragma unroll
    for (int nn = 0; nn < 2; ++nn) {
      int r = 128 + h * D + nn * 16 + (lane & 15);
      bf2v[nn] = *(const short8*)&lds[(r * 128 + kk * 32 + (lane >> 4) * 8) ^ ((r & 7) << 3)];
    }
    #pragma unroll
    for (int m = 0; m < 2; ++m)
      #pragma unroll
      for (int nn = 0; nn < 2; ++nn)
        cacc[m][nn] = __builtin_amdgcn_mfma_f32_16x16x32_bf16(af2[m], bf2v[nn], cacc[m][nn], 0, 0, 0);
  }
  float* cb = cbb + (size_t)h * 1056;
  #pragma unroll
  for (int m = 0; m < 2; ++m)
    #pragma unroll
    for (int nn = 0; nn < 2; ++nn)
      #pragma unroll
      for (int j = 0; j < 4; ++j) {
        int d = m * 16 + (lane >> 4) * 4 + j;
        int e = nn * 16 + (lane & 15);
        cb[d * 32 + e] = cacc[m][nn][j];
      }
}

// ---- reduce partials + normalize + Weff[b][o][h*32+d] = sum_e wout[o][h*32+e]*ctx[d][e] ----
__global__ __launch_bounds__(256) void k_redweff(const float* __restrict__ ctxp,
                                                 const float* __restrict__ wout,
                                                 ushort* __restrict__ Weff) {
  __shared__ float ctxn[D][D + 1];
  __shared__ float ksum[D];
  int bh = blockIdx.x;
  int b = bh >> 2, h = bh & 3;
  int t = threadIdx.x;
  int d = t >> 3, e0 = (t & 7) * 4;
  float vs[4] = {0.f, 0.f, 0.f, 0.f};
  float ks = 0.f;
  for (int s = 0; s < NSPLIT; ++s) {
    const float* cb = ctxp + (size_t)(s * 64 + bh) * 1056;
    f32x4 v = *(const f32x4*)(cb + d * 32 + e0);
    vs[0] += v[0]; vs[1] += v[1]; vs[2] += v[2]; vs[3] += v[3];
    if (t < 32) ks += cb[1024 + t];
  }
  if (t < 32) ksum[t] = ks;
  __syncthreads();
  float rk = 1.f / ksum[d];
  #pragma unroll
  for (int j = 0; j < 4; ++j) ctxn[d][e0 + j] = vs[j] * rk;
  __syncthreads();
  float wrow[D];
  #pragma unroll
  for (int e = 0; e < D; ++e) wrow[e] = wout[t * HID + h * D + e];
  ushort* wb = Weff + ((size_t)(b * C + t)) * HID + h * D;
  #pragma unroll
  for (int g = 0; g < 4; ++g) {
    union { ushort s[8]; uint4 v; } u;
    #pragma unroll
    for (int dj = 0; dj < 8; ++dj) {
      int dd = g * 8 + dj;
      float a = 0.f;
      #pragma unroll
      for (int e = 0; e < D; ++e) a += wrow[e] * ctxn[dd][e];
      u.s[dj] = f2bf(a);
    }
    *(uint4*)(wb + g * 8) = u.v;
  }
}

// ---- GEMM2 (1024 blocks, XCD-swizzled): out[b] = Weff[b] x qT + bias, fused rmsnorm ----
__global__ __launch_bounds__(256) void k_gemm2(const ushort* __restrict__ WeffG,
                                               const ushort* __restrict__ Bm,
                                               const float* __restrict__ bias,
                                               const float* __restrict__ g,
                                               float* __restrict__ outp) {
  const int K = HID;
  __shared__ ushort Abuf[256 * 64];
  __shared__ ushort Bbuf[64 * 64];
  __shared__ float ssred[4][64];
  __shared__ float biasl[C], gl[C];
  int bid = blockIdx.x;
  int work = (bid & 7) * 128 + (bid >> 3);
  int nt = work & 63, b = work >> 6;
  int t = threadIdx.x;
  int lane = t & 63, w = t >> 6;
  int n0 = nt * 64;
  biasl[t] = bias[t];
  gl[t] = g[t];
  const ushort* A = WeffG + (size_t)b * C * K;
  const ushort* Bb = Bm + ((size_t)b * N + n0) * K;
  f32x4 acc[4][4] = {};
  for (int k0 = 0; k0 < K; k0 += 64) {
    #pragma unroll
    for (int i = 0; i < 8; ++i) {
      int chunk = w * 8 + i;
      int row = chunk * 8 + (lane >> 3);
      int col = k0 + (lane & 7) * 8;
      load_lds16(A + (size_t)row * K + col, Abuf + chunk * 512);
    }
    #pragma unroll
    for (int i = 0; i < 2; ++i) {
      int chunk = w * 2 + i;
      int row = chunk * 8 + (lane >> 3);
      int col = k0 + (lane & 7) * 8;
      load_lds16(Bb + (size_t)row * K + col, Bbuf + chunk * 512);
    }
    __syncthreads();
    #pragma unroll
    for (int kk = 0; kk < 2; ++kk) {
      short8 af[4], bfr[4];
      #pragma unroll
      for (int m = 0; m < 4; ++m)
        af[m] = *(const short8*)&Abuf[(w * 64 + m * 16 + (lane & 15)) * 64 + kk * 32 + (lane >> 4) * 8];
      #pragma unroll
      for (int nn = 0; nn < 4; ++nn)
        bfr[nn] = *(const short8*)&Bbuf[(nn * 16 + (lane & 15)) * 64 + kk * 32 + (lane >> 4) * 8];
      #pragma unroll
      for (int m = 0; m < 4; ++m)
        #pragma unroll
        for (int nn = 0; nn < 4; ++nn)
          acc[m][nn] = __builtin_amdgcn_mfma_f32_16x16x32_bf16(af[m], bfr[nn], acc[m][nn], 0, 0, 0);
    }
    __syncthreads();
  }
  #pragma unroll
  for (int m = 0; m < 4; ++m)
    #pragma unroll
    for (int j = 0; j < 4; ++j) {
      int row = w * 64 + m * 16 + (lane >> 4) * 4 + j;
      float bv = biasl[row];
      #pragma unroll
      for (int nn = 0; nn < 4; ++nn) acc[m][nn][j] += bv;
    }
  float ssp[4];
  #pragma unroll
  for (int nn = 0; nn < 4; ++nn) {
    float s = 0.f;
    #pragma unroll
    for (int m = 0; m < 4; ++m)
      #pragma unroll
      for (int j = 0; j < 4; ++j) s += acc[m][nn][j] * acc[m][nn][j];
    s += __shfl_xor(s, 16);
    s += __shfl_xor(s, 32);
    ssp[nn] = s;
  }
  if ((lane >> 4) == 0) {
    #pragma unroll
    for (int nn = 0; nn < 4; ++nn) ssred[w][nn * 16 + (lane & 15)] = ssp[nn];
  }
  __syncthreads();
  float inv[4];
  #pragma unroll
  for (int nn = 0; nn < 4; ++nn) {
    int col = nn * 16 + (lane & 15);
    float tot = ssred[0][col] + ssred[1][col] + ssred[2][col] + ssred[3][col];
    inv[nn] = RMS_MUL / fmaxf(sqrtf(tot), EPS);
  }
  float* Cb = outp + (size_t)b * C * N + n0;
  #pragma unroll
  for (int m = 0; m < 4; ++m)
    #pragma unroll
    for (int j = 0; j < 4; ++j) {
      int row = w * 64 + m * 16 + (lane >> 4) * 4 + j;
      float gm = gl[row];
      #pragma unroll
      for (int nn = 0; nn < 4; ++nn) {
        int col = nn * 16 + (lane & 15);
        Cb[(size_t)row * N + col] = acc[m][nn][j] * inv[nn] * gm;
      }
    }
}

extern "C" void kernel_launch(void* const* d_in, const int* in_sizes, int n_in,
                              void* d_out, int out_size, void* d_ws, size_t ws_size,
                              hipStream_t stream) {
  const float* x    = (const float*)d_in[0];
  const float* gn   = (const float*)d_in[1];
  const float* wqkv = (const float*)d_in[2];
  const float* wout = (const float*)d_in[3];
  const float* bout = (const float*)d_in[4];
  const float* gout = (const float*)d_in[5];
  float* out = (float*)d_out;
  float* ws  = (float*)d_ws;

  ushort* xbf  = (ushort*)ws;                    // 32 MB [b][n][c]
  ushort* qT   = (ushort*)(ws + 8388608);        // 16 MB [b][n][d]
  float*  ctxp = ws + 12582912;                  // 8.65 MB
  ushort* Weff = (ushort*)(ws + 14745600);       // 1 MB
  ushort* wA   = (ushort*)(ws + 15007744);       // 192 KB

  k_prep_w <<<384, 256, 0, stream>>>(wqkv, gn, wA);
  k_prep_x <<<dim3(64, 16), 256, 0, stream>>>(x, xbf);
  k_qgemm  <<<512, 256, 0, stream>>>(wA, xbf, qT);
  k_kvctx  <<<512, 256, 0, stream>>>(wA + 128 * 256, xbf, ctxp);
  k_redweff<<<64, 256, 0, stream>>>(ctxp, wout, Weff);
  k_gemm2  <<<1024, 256, 0, stream>>>(Weff, qT, bout, gout, out);
}

// Round 9
// 109.922 us; speedup vs baseline: 1.1441x; 1.0261x over previous
//
// R9: 4-kernel pipeline. k_qout = q-GEMM + softmax + (Weff x qT) + bias +
//     fused rmsnorm (qT buffer deleted); prep_w merged into k_prep.
//     kvctx/redweff unchanged from R8.
#include <hip/hip_runtime.h>
#include <hip/hip_bf16.h>
#include <math.h>

#define B 16
#define C 256
#define H 4
#define D 32
#define HID 128
#define O3 384
#define N 4096
#define NSPLIT 32
#define QSCALE 0.17677669529663687f  // 1/sqrt(32)
#define RMS_MUL 16.0f                // sqrt(256)
#define EPS 1e-12f

typedef __attribute__((ext_vector_type(8))) short short8;
typedef __attribute__((ext_vector_type(4))) float f32x4;

__device__ __forceinline__ ushort f2bf(float f) {
  __hip_bfloat16 h = __float2bfloat16(f);
  return *(ushort*)&h;
}
__device__ __forceinline__ float bf2f(ushort u) {
  unsigned int v = ((unsigned int)u) << 16;
  return *(float*)&v;
}
__device__ __forceinline__ void load_lds16(const void* g, void* l) {
  __builtin_amdgcn_global_load_lds((const __attribute__((address_space(1))) void*)g,
                                   (__attribute__((address_space(3))) void*)l, 16, 0, 0);
}

// ---- merged prep: blocks 0..383 -> wA; blocks 384..1407 -> x rmsnorm+transpose ----
__global__ __launch_bounds__(256) void k_prep(const float* __restrict__ wqkv,
                                              const float* __restrict__ g,
                                              const float* __restrict__ x,
                                              ushort* __restrict__ wA,
                                              ushort* __restrict__ xbf) {
  __shared__ ushort xl[C][64];
  __shared__ float red[4][64];
  __shared__ float invs[64];
  int t = threadIdx.x;
  if (blockIdx.x < 384) {
    int idx = blockIdx.x * 256 + t;
    wA[idx] = f2bf(wqkv[idx] * g[idx & (C - 1)]);
    return;
  }
  int id = blockIdx.x - 384;
  int w4 = t >> 6, ln = t & 63;
  int b = id >> 6, n0 = (id & 63) * 64;
  const float* xb = x + (size_t)b * C * N + n0;
  float ss = 0.f;
  #pragma unroll
  for (int it = 0; it < 64; ++it) {
    int c = it * 4 + w4;
    float v = xb[(size_t)c * N + ln];
    ss += v * v;
    xl[c][ln] = f2bf(v);
  }
  red[w4][ln] = ss;
  __syncthreads();
  if (t < 64) {
    float tot = red[0][t] + red[1][t] + red[2][t] + red[3][t];
    invs[t] = RMS_MUL / fmaxf(sqrtf(tot), EPS);
  }
  __syncthreads();
  float inv = invs[ln];
  ushort* dst = xbf + ((size_t)(b * N + n0 + ln)) * C + w4 * 64;
  #pragma unroll
  for (int ch = 0; ch < 8; ++ch) {
    union { ushort s[8]; uint4 v; } u;
    #pragma unroll
    for (int j = 0; j < 8; ++j)
      u.s[j] = f2bf(bf2f(xl[w4 * 64 + ch * 8 + j][ln]) * inv);
    *(uint4*)(dst + ch * 8) = u.v;
  }
}

// ---- K/V GEMM + fused context via MFMA epilogue (512 blocks) ----
__global__ __launch_bounds__(256) void k_kvctx(const ushort* __restrict__ A,
                                               const ushort* __restrict__ Bm,
                                               float* __restrict__ ctxp) {
  const int K = 256;
  __shared__ ushort lds[32768];              // 64 KB: staging, then kvt[256][128]
  ushort* Abuf = lds;                        // 256x64
  ushort* Bbuf = lds + 16384;                // 128x64
  int bid = blockIdx.x;
  int work = (bid & 7) * 64 + (bid >> 3);
  int sl = work & 31, b = work >> 5;
  int t = threadIdx.x;
  int lane = t & 63, w = t >> 6;
  int n0 = sl * 128;
  const ushort* Bb = Bm + ((size_t)b * N + n0) * K;
  f32x4 acc[4][8] = {};
  for (int k0 = 0; k0 < K; k0 += 64) {
    #pragma unroll
    for (int i = 0; i < 8; ++i) {
      int chunk = w * 8 + i;
      int row = chunk * 8 + (lane >> 3);
      int col = k0 + (lane & 7) * 8;
      load_lds16(A + (size_t)row * K + col, Abuf + chunk * 512);
    }
    #pragma unroll
    for (int i = 0; i < 4; ++i) {
      int chunk = w * 4 + i;
      int row = chunk * 8 + (lane >> 3);
      int col = k0 + (lane & 7) * 8;
      load_lds16(Bb + (size_t)row * K + col, Bbuf + chunk * 512);
    }
    __syncthreads();
    #pragma unroll
    for (int kk = 0; kk < 2; ++kk) {
      short8 af[4], bfr[8];
      #pragma unroll
      for (int m = 0; m < 4; ++m)
        af[m] = *(const short8*)&Abuf[(w * 64 + m * 16 + (lane & 15)) * 64 + kk * 32 + (lane >> 4) * 8];
      #pragma unroll
      for (int nn = 0; nn < 8; ++nn)
        bfr[nn] = *(const short8*)&Bbuf[(nn * 16 + (lane & 15)) * 64 + kk * 32 + (lane >> 4) * 8];
      #pragma unroll
      for (int m = 0; m < 4; ++m)
        #pragma unroll
        for (int nn = 0; nn < 8; ++nn)
          acc[m][nn] = __builtin_amdgcn_mfma_f32_16x16x32_bf16(af[m], bfr[nn], acc[m][nn], 0, 0, 0);
    }
    __syncthreads();
  }
  float* cbb = ctxp + (size_t)(sl * 64 + b * 4) * 1056;
  if (w < 2) {
    #pragma unroll
    for (int m = 0; m < 4; ++m)
      #pragma unroll
      for (int nn = 0; nn < 8; ++nn)
        #pragma unroll
        for (int j = 0; j < 4; ++j) acc[m][nn][j] = __expf(acc[m][nn][j]);
    #pragma unroll
    for (int m = 0; m < 4; ++m)
      #pragma unroll
      for (int j = 0; j < 4; ++j) {
        float s = 0.f;
        #pragma unroll
        for (int nn = 0; nn < 8; ++nn) s += acc[m][nn][j];
        s += __shfl_xor(s, 1); s += __shfl_xor(s, 2);
        s += __shfl_xor(s, 4); s += __shfl_xor(s, 8);
        if ((lane & 15) == 0) {
          int r = w * 64 + m * 16 + (lane >> 4) * 4 + j;
          cbb[(size_t)(r >> 5) * 1056 + 1024 + (r & 31)] = s;
        }
      }
  }
  #pragma unroll
  for (int m = 0; m < 4; ++m)
    #pragma unroll
    for (int nn = 0; nn < 8; ++nn) {
      int r0 = w * 64 + m * 16 + (lane >> 4) * 4;
      int n = nn * 16 + (lane & 15);
      #pragma unroll
      for (int j = 0; j < 4; ++j) {
        int r = r0 + j;
        lds[(r * 128 + n) ^ ((r & 7) << 3)] = f2bf(acc[m][nn][j]);
      }
    }
  __syncthreads();
  int h = w;
  f32x4 cacc[2][2] = {};
  #pragma unroll
  for (int kk = 0; kk < 4; ++kk) {
    short8 af2[2], bf2v[2];
    #pragma unroll
    for (int m = 0; m < 2; ++m) {
      int r = h * D + m * 16 + (lane & 15);
      af2[m] = *(const short8*)&lds[(r * 128 + kk * 32 + (lane >> 4) * 8) ^ ((r & 7) << 3)];
    }
    #pragma unroll
    for (int nn = 0; nn < 2; ++nn) {
      int r = 128 + h * D + nn * 16 + (lane & 15);
      bf2v[nn] = *(const short8*)&lds[(r * 128 + kk * 32 + (lane >> 4) * 8) ^ ((r & 7) << 3)];
    }
    #pragma unroll
    for (int m = 0; m < 2; ++m)
      #pragma unroll
      for (int nn = 0; nn < 2; ++nn)
        cacc[m][nn] = __builtin_amdgcn_mfma_f32_16x16x32_bf16(af2[m], bf2v[nn], cacc[m][nn], 0, 0, 0);
  }
  float* cb = cbb + (size_t)h * 1056;
  #pragma unroll
  for (int m = 0; m < 2; ++m)
    #pragma unroll
    for (int nn = 0; nn < 2; ++nn)
      #pragma unroll
      for (int j = 0; j < 4; ++j) {
        int d = m * 16 + (lane >> 4) * 4 + j;
        int e = nn * 16 + (lane & 15);
        cb[d * 32 + e] = cacc[m][nn][j];
      }
}

// ---- reduce partials + normalize + Weff build ----
__global__ __launch_bounds__(256) void k_redweff(const float* __restrict__ ctxp,
                                                 const float* __restrict__ wout,
                                                 ushort* __restrict__ Weff) {
  __shared__ float ctxn[D][D + 1];
  __shared__ float ksum[D];
  int bh = blockIdx.x;
  int b = bh >> 2, h = bh & 3;
  int t = threadIdx.x;
  int d = t >> 3, e0 = (t & 7) * 4;
  float vs[4] = {0.f, 0.f, 0.f, 0.f};
  float ks = 0.f;
  for (int s = 0; s < NSPLIT; ++s) {
    const float* cb = ctxp + (size_t)(s * 64 + bh) * 1056;
    f32x4 v = *(const f32x4*)(cb + d * 32 + e0);
    vs[0] += v[0]; vs[1] += v[1]; vs[2] += v[2]; vs[3] += v[3];
    if (t < 32) ks += cb[1024 + t];
  }
  if (t < 32) ksum[t] = ks;
  __syncthreads();
  float rk = 1.f / ksum[d];
  #pragma unroll
  for (int j = 0; j < 4; ++j) ctxn[d][e0 + j] = vs[j] * rk;
  __syncthreads();
  float wrow[D];
  #pragma unroll
  for (int e = 0; e < D; ++e) wrow[e] = wout[t * HID + h * D + e];
  ushort* wb = Weff + ((size_t)(b * C + t)) * HID + h * D;
  #pragma unroll
  for (int g = 0; g < 4; ++g) {
    union { ushort s[8]; uint4 v; } u;
    #pragma unroll
    for (int dj = 0; dj < 8; ++dj) {
      int dd = g * 8 + dj;
      float a = 0.f;
      #pragma unroll
      for (int e = 0; e < D; ++e) a += wrow[e] * ctxn[dd][e];
      u.s[dj] = f2bf(a);
    }
    *(uint4*)(wb + g * 8) = u.v;
  }
}

// ---- fused q-GEMM + softmax + (Weff x qT) + bias + rmsnorm (512 blocks) ----
__global__ __launch_bounds__(256) void k_qout(const ushort* __restrict__ A,
                                              const ushort* __restrict__ Bm,
                                              const ushort* __restrict__ WeffG,
                                              const float* __restrict__ bias,
                                              const float* __restrict__ g,
                                              float* __restrict__ outp) {
  const int K = 256;
  __shared__ ushort lds[32768];       // 64 KB: [0..16K) staging, [16K..32K) q[n][d]
  ushort* Abuf = lds;                 // ph1: 128x64 at [0..8K); ph2: 256x64 at [0..16K)
  ushort* Bbuf = lds + 8192;
  ushort* qlds = lds + 16384;         // [128 n][128 d]
  int bid = blockIdx.x;
  int work = (bid & 7) * 64 + (bid >> 3);
  int xt = work & 31, b = work >> 5;
  int t = threadIdx.x;
  int lane = t & 63, w = t >> 6;
  int wr = w >> 1, wc = w & 1;
  int n0 = xt * 128;
  const ushort* Bb = Bm + ((size_t)b * N + n0) * K;
  // ---- phase 1: q GEMM (128x128, K=256) + softmax + LDS dump ----
  {
    f32x4 acc[4][4] = {};
    for (int k0 = 0; k0 < K; k0 += 64) {
      #pragma unroll
      for (int i = 0; i < 4; ++i) {
        int chunk = w * 4 + i;
        int row = chunk * 8 + (lane >> 3);
        int col = k0 + (lane & 7) * 8;
        load_lds16(A + (size_t)row * K + col, Abuf + chunk * 512);
        load_lds16(Bb + (size_t)row * K + col, Bbuf + chunk * 512);
      }
      __syncthreads();
      #pragma unroll
      for (int kk = 0; kk < 2; ++kk) {
        short8 af[4], bfr[4];
        #pragma unroll
        for (int m = 0; m < 4; ++m)
          af[m] = *(const short8*)&Abuf[(wr * 64 + m * 16 + (lane & 15)) * 64 + kk * 32 + (lane >> 4) * 8];
        #pragma unroll
        for (int nn = 0; nn < 4; ++nn)
          bfr[nn] = *(const short8*)&Bbuf[(wc * 64 + nn * 16 + (lane & 15)) * 64 + kk * 32 + (lane >> 4) * 8];
        #pragma unroll
        for (int m = 0; m < 4; ++m)
          #pragma unroll
          for (int nn = 0; nn < 4; ++nn)
            acc[m][nn] = __builtin_amdgcn_mfma_f32_16x16x32_bf16(af[m], bfr[nn], acc[m][nn], 0, 0, 0);
      }
      __syncthreads();
    }
    #pragma unroll
    for (int hh = 0; hh < 2; ++hh) {
      #pragma unroll
      for (int nn = 0; nn < 4; ++nn) {
        int m0 = hh * 2;
        float pm = -1e30f;
        #pragma unroll
        for (int mi = 0; mi < 2; ++mi)
          #pragma unroll
          for (int j = 0; j < 4; ++j) pm = fmaxf(pm, acc[m0 + mi][nn][j]);
        pm = fmaxf(pm, __shfl_xor(pm, 16));
        pm = fmaxf(pm, __shfl_xor(pm, 32));
        float e[2][4], ps = 0.f;
        #pragma unroll
        for (int mi = 0; mi < 2; ++mi)
          #pragma unroll
          for (int j = 0; j < 4; ++j) {
            e[mi][j] = __expf(acc[m0 + mi][nn][j] - pm);
            ps += e[mi][j];
          }
        ps += __shfl_xor(ps, 16);
        ps += __shfl_xor(ps, 32);
        float rs = QSCALE / ps;
        #pragma unroll
        for (int mi = 0; mi < 2; ++mi)
          #pragma unroll
          for (int j = 0; j < 4; ++j) acc[m0 + mi][nn][j] = e[mi][j] * rs;
      }
    }
    #pragma unroll
    for (int m = 0; m < 4; ++m)
      #pragma unroll
      for (int nn = 0; nn < 4; ++nn) {
        int d0 = wr * 64 + m * 16 + (lane >> 4) * 4;
        int n = wc * 64 + nn * 16 + (lane & 15);
        union { ushort us[4]; uint2 v; } u;
        #pragma unroll
        for (int j = 0; j < 4; ++j) u.us[j] = f2bf(acc[m][nn][j]);
        *(uint2*)&qlds[(n * 128 + d0) ^ ((n & 7) << 3)] = u.v;
      }
  }
  __syncthreads();
  // ---- phase 2: out = Weff[b] (256x128) x q^T (128 n), K=128 ----
  const ushort* Aw = WeffG + (size_t)b * C * HID;
  f32x4 acc2[4][8] = {};
  for (int k0 = 0; k0 < HID; k0 += 64) {
    #pragma unroll
    for (int i = 0; i < 8; ++i) {
      int chunk = w * 8 + i;                 // rows 0..255
      int row = chunk * 8 + (lane >> 3);
      int col = k0 + (lane & 7) * 8;
      load_lds16(Aw + (size_t)row * HID + col, Abuf + chunk * 512);
    }
    __syncthreads();
    #pragma unroll
    for (int kk = 0; kk < 2; ++kk) {
      short8 af[4], bfr[8];
      #pragma unroll
      for (int m = 0; m < 4; ++m)
        af[m] = *(const short8*)&Abuf[(w * 64 + m * 16 + (lane & 15)) * 64 + kk * 32 + (lane >> 4) * 8];
      #pragma unroll
      for (int nn = 0; nn < 8; ++nn) {
        int n = nn * 16 + (lane & 15);
        bfr[nn] = *(const short8*)&qlds[(n * 128 + k0 + kk * 32 + (lane >> 4) * 8) ^ ((n & 7) << 3)];
      }
      #pragma unroll
      for (int m = 0; m < 4; ++m)
        #pragma unroll
        for (int nn = 0; nn < 8; ++nn)
          acc2[m][nn] = __builtin_amdgcn_mfma_f32_16x16x32_bf16(af[m], bfr[nn], acc2[m][nn], 0, 0, 0);
    }
    __syncthreads();
  }
  // ---- epilogue: bias + per-column rmsnorm + write (staging LDS now dead) ----
  float* ssred = (float*)lds;                // [4][128]
  float* biasl = (float*)lds + 512;          // [256]
  float* gl    = (float*)lds + 768;          // [256]
  biasl[t] = bias[t];
  gl[t] = g[t];
  #pragma unroll
  for (int m = 0; m < 4; ++m)
    #pragma unroll
    for (int j = 0; j < 4; ++j) {
      int row = w * 64 + m * 16 + (lane >> 4) * 4 + j;
      float bv = bias[row];
      #pragma unroll
      for (int nn = 0; nn < 8; ++nn) acc2[m][nn][j] += bv;
    }
  float ssp[8];
  #pragma unroll
  for (int nn = 0; nn < 8; ++nn) {
    float s = 0.f;
    #pragma unroll
    for (int m = 0; m < 4; ++m)
      #pragma unroll
      for (int j = 0; j < 4; ++j) s += acc2[m][nn][j] * acc2[m][nn][j];
    s += __shfl_xor(s, 16);
    s += __shfl_xor(s, 32);
    ssp[nn] = s;
  }
  if ((lane >> 4) == 0) {
    #pragma unroll
    for (int nn = 0; nn < 8; ++nn) ssred[w * 128 + nn * 16 + (lane & 15)] = ssp[nn];
  }
  __syncthreads();
  float inv[8];
  #pragma unroll
  for (int nn = 0; nn < 8; ++nn) {
    int col = nn * 16 + (lane & 15);
    float tot = ssred[col] + ssred[128 + col] + ssred[256 + col] + ssred[384 + col];
    inv[nn] = RMS_MUL / fmaxf(sqrtf(tot), EPS);
  }
  float* Cb = outp + (size_t)b * C * N + n0;
  #pragma unroll
  for (int m = 0; m < 4; ++m)
    #pragma unroll
    for (int j = 0; j < 4; ++j) {
      int row = w * 64 + m * 16 + (lane >> 4) * 4 + j;
      float gm = gl[row];
      #pragma unroll
      for (int nn = 0; nn < 8; ++nn) {
        int col = nn * 16 + (lane & 15);
        Cb[(size_t)row * N + col] = acc2[m][nn][j] * inv[nn] * gm;
      }
    }
}

extern "C" void kernel_launch(void* const* d_in, const int* in_sizes, int n_in,
                              void* d_out, int out_size, void* d_ws, size_t ws_size,
                              hipStream_t stream) {
  const float* x    = (const float*)d_in[0];
  const float* gn   = (const float*)d_in[1];
  const float* wqkv = (const float*)d_in[2];
  const float* wout = (const float*)d_in[3];
  const float* bout = (const float*)d_in[4];
  const float* gout = (const float*)d_in[5];
  float* out = (float*)d_out;
  float* ws  = (float*)d_ws;

  ushort* xbf  = (ushort*)ws;                    // 32 MB [b][n][c]
  float*  ctxp = ws + 8388608;                   // 8.65 MB
  ushort* Weff = (ushort*)(ws + 10551296);       // 1 MB
  ushort* wA   = (ushort*)(ws + 10813440);       // 192 KB
  // total ~43.5 MB

  k_prep   <<<1408, 256, 0, stream>>>(wqkv, gn, x, wA, xbf);
  k_kvctx  <<<512, 256, 0, stream>>>(wA + 128 * 256, xbf, ctxp);
  k_redweff<<<64, 256, 0, stream>>>(ctxp, wout, Weff);
  k_qout   <<<512, 256, 0, stream>>>(wA, xbf, Weff, bout, gout, out);
}

// Round 10
// 87.445 us; speedup vs baseline: 1.4382x; 1.2570x over previous
//
// R10: double parallelism. kvctx M-split by head-pairs (grid 1024, 32 KB LDS,
//      4 blk/CU); qout N-split to 64 (grid 1024, 32 KB LDS, ph2 BK=32).
//      __launch_bounds__(256,4) on both. prep/redweff unchanged.
#include <hip/hip_runtime.h>
#include <hip/hip_bf16.h>
#include <math.h>

#define B 16
#define C 256
#define H 4
#define D 32
#define HID 128
#define O3 384
#define N 4096
#define NSPLIT 32
#define QSCALE 0.17677669529663687f  // 1/sqrt(32)
#define RMS_MUL 16.0f                // sqrt(256)
#define EPS 1e-12f

typedef __attribute__((ext_vector_type(8))) short short8;
typedef __attribute__((ext_vector_type(4))) float f32x4;

__device__ __forceinline__ ushort f2bf(float f) {
  __hip_bfloat16 h = __float2bfloat16(f);
  return *(ushort*)&h;
}
__device__ __forceinline__ float bf2f(ushort u) {
  unsigned int v = ((unsigned int)u) << 16;
  return *(float*)&v;
}
__device__ __forceinline__ void load_lds16(const void* g, void* l) {
  __builtin_amdgcn_global_load_lds((const __attribute__((address_space(1))) void*)g,
                                   (__attribute__((address_space(3))) void*)l, 16, 0, 0);
}

// ---- merged prep: blocks 0..383 -> wA; blocks 384..1407 -> x rmsnorm+transpose ----
__global__ __launch_bounds__(256) void k_prep(const float* __restrict__ wqkv,
                                              const float* __restrict__ g,
                                              const float* __restrict__ x,
                                              ushort* __restrict__ wA,
                                              ushort* __restrict__ xbf) {
  __shared__ ushort xl[C][64];
  __shared__ float red[4][64];
  __shared__ float invs[64];
  int t = threadIdx.x;
  if (blockIdx.x < 384) {
    int idx = blockIdx.x * 256 + t;
    wA[idx] = f2bf(wqkv[idx] * g[idx & (C - 1)]);
    return;
  }
  int id = blockIdx.x - 384;
  int w4 = t >> 6, ln = t & 63;
  int b = id >> 6, n0 = (id & 63) * 64;
  const float* xb = x + (size_t)b * C * N + n0;
  float ss = 0.f;
  #pragma unroll
  for (int it = 0; it < 64; ++it) {
    int c = it * 4 + w4;
    float v = xb[(size_t)c * N + ln];
    ss += v * v;
    xl[c][ln] = f2bf(v);
  }
  red[w4][ln] = ss;
  __syncthreads();
  if (t < 64) {
    float tot = red[0][t] + red[1][t] + red[2][t] + red[3][t];
    invs[t] = RMS_MUL / fmaxf(sqrtf(tot), EPS);
  }
  __syncthreads();
  float inv = invs[ln];
  ushort* dst = xbf + ((size_t)(b * N + n0 + ln)) * C + w4 * 64;
  #pragma unroll
  for (int ch = 0; ch < 8; ++ch) {
    union { ushort s[8]; uint4 v; } u;
    #pragma unroll
    for (int j = 0; j < 8; ++j)
      u.s[j] = f2bf(bf2f(xl[w4 * 64 + ch * 8 + j][ln]) * inv);
    *(uint4*)(dst + ch * 8) = u.v;
  }
}

// ---- K/V GEMM + fused context, M-split by head pair (1024 blocks) ----
// Block (mh): k-rows mh*64..+64 (heads 2mh,2mh+1), v-rows 128+mh*64..+64.
__global__ __launch_bounds__(256, 4) void k_kvctx(const ushort* __restrict__ A,
                                                  const ushort* __restrict__ Bm,
                                                  float* __restrict__ ctxp) {
  const int K = 256;
  __shared__ ushort lds[16384];              // 32 KB: A[128][64]+B[128][64]; then kvt[128][128]
  ushort* Abuf = lds;
  ushort* Bbuf = lds + 8192;
  int bid = blockIdx.x;
  int work = (bid & 7) * 128 + (bid >> 3);
  int mh = work & 1, sl = (work >> 1) & 31, b = work >> 6;
  int t = threadIdx.x;
  int lane = t & 63, w = t >> 6;
  int n0 = sl * 128;
  const ushort* Bb = Bm + ((size_t)b * N + n0) * K;
  f32x4 acc[2][8] = {};
  for (int k0 = 0; k0 < K; k0 += 64) {
    #pragma unroll
    for (int i = 0; i < 4; ++i) {
      int c = w * 4 + i;
      int lr = c * 8 + (lane >> 3);                       // 0..127 local
      int gr = mh * 64 + (lr & 63) + ((lr & 64) << 1);    // global kv row
      int col = k0 + (lane & 7) * 8;
      load_lds16(A + (size_t)gr * K + col, Abuf + c * 512);
    }
    #pragma unroll
    for (int i = 0; i < 4; ++i) {
      int c = w * 4 + i;
      int row = c * 8 + (lane >> 3);
      int col = k0 + (lane & 7) * 8;
      load_lds16(Bb + (size_t)row * K + col, Bbuf + c * 512);
    }
    __syncthreads();
    #pragma unroll
    for (int kk = 0; kk < 2; ++kk) {
      short8 af[2], bfr[8];
      #pragma unroll
      for (int m = 0; m < 2; ++m)
        af[m] = *(const short8*)&Abuf[(w * 32 + m * 16 + (lane & 15)) * 64 + kk * 32 + (lane >> 4) * 8];
      #pragma unroll
      for (int nn = 0; nn < 8; ++nn)
        bfr[nn] = *(const short8*)&Bbuf[(nn * 16 + (lane & 15)) * 64 + kk * 32 + (lane >> 4) * 8];
      #pragma unroll
      for (int m = 0; m < 2; ++m)
        #pragma unroll
        for (int nn = 0; nn < 8; ++nn)
          acc[m][nn] = __builtin_amdgcn_mfma_f32_16x16x32_bf16(af[m], bfr[nn], acc[m][nn], 0, 0, 0);
    }
    __syncthreads();
  }
  float* cbb = ctxp + (size_t)(sl * 64 + b * 4) * 1056;
  // k waves (local rows 0..63): exp in-register + ksum
  if (w < 2) {
    #pragma unroll
    for (int m = 0; m < 2; ++m)
      #pragma unroll
      for (int nn = 0; nn < 8; ++nn)
        #pragma unroll
        for (int j = 0; j < 4; ++j) acc[m][nn][j] = __expf(acc[m][nn][j]);
    #pragma unroll
    for (int m = 0; m < 2; ++m)
      #pragma unroll
      for (int j = 0; j < 4; ++j) {
        float s = 0.f;
        #pragma unroll
        for (int nn = 0; nn < 8; ++nn) s += acc[m][nn][j];
        s += __shfl_xor(s, 1); s += __shfl_xor(s, 2);
        s += __shfl_xor(s, 4); s += __shfl_xor(s, 8);
        if ((lane & 15) == 0) {
          int lr = w * 32 + m * 16 + (lane >> 4) * 4 + j;  // 0..63
          int h = mh * 2 + (lr >> 5);
          cbb[(size_t)h * 1056 + 1024 + (lr & 31)] = s;
        }
      }
  }
  // dump kvt[128 local rows][128 n], swizzled (staging dead)
  #pragma unroll
  for (int m = 0; m < 2; ++m)
    #pragma unroll
    for (int nn = 0; nn < 8; ++nn) {
      int lr0 = w * 32 + m * 16 + (lane >> 4) * 4;
      int n = nn * 16 + (lane & 15);
      #pragma unroll
      for (int j = 0; j < 4; ++j) {
        int lr = lr0 + j;
        lds[(lr * 128 + n) ^ ((lr & 7) << 3)] = f2bf(acc[m][nn][j]);
      }
    }
  __syncthreads();
  // ctx via MFMA: wave -> (head-half hl, e-half eh); M=32 d x N=16 e x K=128 n
  int hl = w >> 1, eh = w & 1;
  f32x4 cacc[2] = {};
  #pragma unroll
  for (int kk = 0; kk < 4; ++kk) {
    short8 af2[2], bv;
    #pragma unroll
    for (int m = 0; m < 2; ++m) {
      int lrk = hl * 32 + m * 16 + (lane & 15);
      af2[m] = *(const short8*)&lds[(lrk * 128 + kk * 32 + (lane >> 4) * 8) ^ ((lrk & 7) << 3)];
    }
    int lrv = 64 + hl * 32 + eh * 16 + (lane & 15);
    bv = *(const short8*)&lds[(lrv * 128 + kk * 32 + (lane >> 4) * 8) ^ ((lrv & 7) << 3)];
    #pragma unroll
    for (int m = 0; m < 2; ++m)
      cacc[m] = __builtin_amdgcn_mfma_f32_16x16x32_bf16(af2[m], bv, cacc[m], 0, 0, 0);
  }
  int hg = mh * 2 + hl;
  float* cb = ctxp + (size_t)(sl * 64 + b * 4 + hg) * 1056;
  #pragma unroll
  for (int m = 0; m < 2; ++m)
    #pragma unroll
    for (int j = 0; j < 4; ++j) {
      int d = m * 16 + (lane >> 4) * 4 + j;
      int e = eh * 16 + (lane & 15);
      cb[d * 32 + e] = cacc[m][j];
    }
}

// ---- reduce partials + normalize + Weff build (64 blocks) ----
__global__ __launch_bounds__(256) void k_redweff(const float* __restrict__ ctxp,
                                                 const float* __restrict__ wout,
                                                 ushort* __restrict__ Weff) {
  __shared__ float ctxn[D][D + 1];
  __shared__ float ksum[D];
  int bh = blockIdx.x;
  int b = bh >> 2, h = bh & 3;
  int t = threadIdx.x;
  int d = t >> 3, e0 = (t & 7) * 4;
  float vs[4] = {0.f, 0.f, 0.f, 0.f};
  float ks = 0.f;
  for (int s = 0; s < NSPLIT; ++s) {
    const float* cb = ctxp + (size_t)(s * 64 + bh) * 1056;
    f32x4 v = *(const f32x4*)(cb + d * 32 + e0);
    vs[0] += v[0]; vs[1] += v[1]; vs[2] += v[2]; vs[3] += v[3];
    if (t < 32) ks += cb[1024 + t];
  }
  if (t < 32) ksum[t] = ks;
  __syncthreads();
  float rk = 1.f / ksum[d];
  #pragma unroll
  for (int j = 0; j < 4; ++j) ctxn[d][e0 + j] = vs[j] * rk;
  __syncthreads();
  float wrow[D];
  #pragma unroll
  for (int e = 0; e < D; ++e) wrow[e] = wout[t * HID + h * D + e];
  ushort* wb = Weff + ((size_t)(b * C + t)) * HID + h * D;
  #pragma unroll
  for (int g = 0; g < 4; ++g) {
    union { ushort s[8]; uint4 v; } u;
    #pragma unroll
    for (int dj = 0; dj < 8; ++dj) {
      int dd = g * 8 + dj;
      float a = 0.f;
      #pragma unroll
      for (int e = 0; e < D; ++e) a += wrow[e] * ctxn[dd][e];
      u.s[dj] = f2bf(a);
    }
    *(uint4*)(wb + g * 8) = u.v;
  }
}

// ---- fused q-GEMM + softmax + (Weff x qT) + bias + rmsnorm (1024 blocks, N=64) ----
__global__ __launch_bounds__(256, 4) void k_qout(const ushort* __restrict__ A,
                                                 const ushort* __restrict__ Bm,
                                                 const ushort* __restrict__ WeffG,
                                                 const float* __restrict__ bias,
                                                 const float* __restrict__ g,
                                                 float* __restrict__ outp) {
  const int K = 256;
  __shared__ ushort lds[16384];       // 32 KB
  ushort* Abuf = lds;                 // ph1 A [128][64] = 8192 us
  ushort* Bbuf = lds + 8192;          // ph1 B [64][64] = 4096 us
  ushort* qlds = lds + 8192;          // q [64 n][128 d] = 8192 us (after ph1)
  ushort* A2buf = lds;                // ph2 A [256][32] = 8192 us
  int bid = blockIdx.x;
  int work = (bid & 7) * 128 + (bid >> 3);
  int xt = work & 63, b = work >> 6;
  int t = threadIdx.x;
  int lane = t & 63, w = t >> 6;
  int n0 = xt * 64;
  const ushort* Bb = Bm + ((size_t)b * N + n0) * K;
  // ---- phase 1: q GEMM (128 d x 64 n, K=256) + per-head softmax + qlds dump ----
  {
    f32x4 acc[2][4] = {};
    for (int k0 = 0; k0 < K; k0 += 64) {
      #pragma unroll
      for (int i = 0; i < 4; ++i) {
        int c = w * 4 + i;
        int row = c * 8 + (lane >> 3);
        int col = k0 + (lane & 7) * 8;
        load_lds16(A + (size_t)row * K + col, Abuf + c * 512);
      }
      #pragma unroll
      for (int i = 0; i < 2; ++i) {
        int c = w * 2 + i;
        int row = c * 8 + (lane >> 3);
        int col = k0 + (lane & 7) * 8;
        load_lds16(Bb + (size_t)row * K + col, Bbuf + c * 512);
      }
      __syncthreads();
      #pragma unroll
      for (int kk = 0; kk < 2; ++kk) {
        short8 af[2], bfr[4];
        #pragma unroll
        for (int m = 0; m < 2; ++m)
          af[m] = *(const short8*)&Abuf[(w * 32 + m * 16 + (lane & 15)) * 64 + kk * 32 + (lane >> 4) * 8];
        #pragma unroll
        for (int nn = 0; nn < 4; ++nn)
          bfr[nn] = *(const short8*)&Bbuf[(nn * 16 + (lane & 15)) * 64 + kk * 32 + (lane >> 4) * 8];
        #pragma unroll
        for (int m = 0; m < 2; ++m)
          #pragma unroll
          for (int nn = 0; nn < 4; ++nn)
            acc[m][nn] = __builtin_amdgcn_mfma_f32_16x16x32_bf16(af[m], bfr[nn], acc[m][nn], 0, 0, 0);
      }
      __syncthreads();
    }
    // softmax over this wave's head (rows w*32..w*32+31) per column
    #pragma unroll
    for (int nn = 0; nn < 4; ++nn) {
      float pm = -1e30f;
      #pragma unroll
      for (int m = 0; m < 2; ++m)
        #pragma unroll
        for (int j = 0; j < 4; ++j) pm = fmaxf(pm, acc[m][nn][j]);
      pm = fmaxf(pm, __shfl_xor(pm, 16));
      pm = fmaxf(pm, __shfl_xor(pm, 32));
      float e[2][4], ps = 0.f;
      #pragma unroll
      for (int m = 0; m < 2; ++m)
        #pragma unroll
        for (int j = 0; j < 4; ++j) {
          e[m][j] = __expf(acc[m][nn][j] - pm);
          ps += e[m][j];
        }
      ps += __shfl_xor(ps, 16);
      ps += __shfl_xor(ps, 32);
      float rs = QSCALE / ps;
      #pragma unroll
      for (int m = 0; m < 2; ++m)
        #pragma unroll
        for (int j = 0; j < 4; ++j) acc[m][nn][j] = e[m][j] * rs;
    }
    // dump q to qlds[n][d] (swizzled); Bbuf region dead
    #pragma unroll
    for (int m = 0; m < 2; ++m)
      #pragma unroll
      for (int nn = 0; nn < 4; ++nn) {
        int d0 = w * 32 + m * 16 + (lane >> 4) * 4;
        int n = nn * 16 + (lane & 15);
        union { ushort us[4]; uint2 v; } u;
        #pragma unroll
        for (int j = 0; j < 4; ++j) u.us[j] = f2bf(acc[m][nn][j]);
        *(uint2*)&qlds[(n * 128 + d0) ^ ((n & 7) << 3)] = u.v;
      }
  }
  __syncthreads();
  // ---- phase 2: out = Weff[b] (256x128) x qT (64 n), BK=32 ----
  const ushort* Aw = WeffG + (size_t)b * C * HID;
  f32x4 acc2[4][4] = {};
  for (int k0 = 0; k0 < HID; k0 += 32) {
    #pragma unroll
    for (int i = 0; i < 4; ++i) {
      int c = w * 4 + i;                       // 0..15, 16 rows each
      int row = c * 16 + (lane >> 2);
      int col = k0 + (lane & 3) * 8;
      load_lds16(Aw + (size_t)row * HID + col, A2buf + c * 512);
    }
    __syncthreads();
    short8 af[4], bfr[4];
    #pragma unroll
    for (int m = 0; m < 4; ++m)
      af[m] = *(const short8*)&A2buf[(w * 64 + m * 16 + (lane & 15)) * 32 + (lane >> 4) * 8];
    #pragma unroll
    for (int nn = 0; nn < 4; ++nn) {
      int n = nn * 16 + (lane & 15);
      bfr[nn] = *(const short8*)&qlds[(n * 128 + k0 + (lane >> 4) * 8) ^ ((n & 7) << 3)];
    }
    #pragma unroll
    for (int m = 0; m < 4; ++m)
      #pragma unroll
      for (int nn = 0; nn < 4; ++nn)
        acc2[m][nn] = __builtin_amdgcn_mfma_f32_16x16x32_bf16(af[m], bfr[nn], acc2[m][nn], 0, 0, 0);
    __syncthreads();
  }
  // ---- epilogue: bias + per-column rmsnorm + write ----
  float* ssred = (float*)lds;                  // [4][64] floats (A2buf dead)
  #pragma unroll
  for (int m = 0; m < 4; ++m)
    #pragma unroll
    for (int j = 0; j < 4; ++j) {
      int row = w * 64 + m * 16 + (lane >> 4) * 4 + j;
      float bv = bias[row];
      #pragma unroll
      for (int nn = 0; nn < 4; ++nn) acc2[m][nn][j] += bv;
    }
  float ssp[4];
  #pragma unroll
  for (int nn = 0; nn < 4; ++nn) {
    float s = 0.f;
    #pragma unroll
    for (int m = 0; m < 4; ++m)
      #pragma unroll
      for (int j = 0; j < 4; ++j) s += acc2[m][nn][j] * acc2[m][nn][j];
    s += __shfl_xor(s, 16);
    s += __shfl_xor(s, 32);
    ssp[nn] = s;
  }
  if ((lane >> 4) == 0) {
    #pragma unroll
    for (int nn = 0; nn < 4; ++nn) ssred[w * 64 + nn * 16 + (lane & 15)] = ssp[nn];
  }
  __syncthreads();
  float inv[4];
  #pragma unroll
  for (int nn = 0; nn < 4; ++nn) {
    int col = nn * 16 + (lane & 15);
    float tot = ssred[col] + ssred[64 + col] + ssred[128 + col] + ssred[192 + col];
    inv[nn] = RMS_MUL / fmaxf(sqrtf(tot), EPS);
  }
  float* Cb = outp + (size_t)b * C * N + n0;
  #pragma unroll
  for (int m = 0; m < 4; ++m)
    #pragma unroll
    for (int j = 0; j < 4; ++j) {
      int row = w * 64 + m * 16 + (lane >> 4) * 4 + j;
      float gm = g[row];
      #pragma unroll
      for (int nn = 0; nn < 4; ++nn) {
        int col = nn * 16 + (lane & 15);
        Cb[(size_t)row * N + col] = acc2[m][nn][j] * inv[nn] * gm;
      }
    }
}

extern "C" void kernel_launch(void* const* d_in, const int* in_sizes, int n_in,
                              void* d_out, int out_size, void* d_ws, size_t ws_size,
                              hipStream_t stream) {
  const float* x    = (const float*)d_in[0];
  const float* gn   = (const float*)d_in[1];
  const float* wqkv = (const float*)d_in[2];
  const float* wout = (const float*)d_in[3];
  const float* bout = (const float*)d_in[4];
  const float* gout = (const float*)d_in[5];
  float* out = (float*)d_out;
  float* ws  = (float*)d_ws;

  ushort* xbf  = (ushort*)ws;                    // 32 MB [b][n][c]
  float*  ctxp = ws + 8388608;                   // 8.65 MB
  ushort* Weff = (ushort*)(ws + 10551296);       // 1 MB
  ushort* wA   = (ushort*)(ws + 10813440);       // 192 KB

  k_prep   <<<1408, 256, 0, stream>>>(wqkv, gn, x, wA, xbf);
  k_kvctx  <<<1024, 256, 0, stream>>>(wA + 128 * 256, xbf, ctxp);
  k_redweff<<<64, 256, 0, stream>>>(ctxp, wout, Weff);
  k_qout   <<<1024, 256, 0, stream>>>(wA, xbf, Weff, bout, gout, out);
}

// Round 11
// 86.301 us; speedup vs baseline: 1.4573x; 1.0133x over previous
//
// R11: k_prep x-path rewritten register-direct (thread reads what it writes,
//      no LDS data round-trip, single bf16 rounding, 2048 finer blocks).
//      kvctx/redweff/qout byte-identical to R10.
#include <hip/hip_runtime.h>
#include <hip/hip_bf16.h>
#include <math.h>

#define B 16
#define C 256
#define H 4
#define D 32
#define HID 128
#define O3 384
#define N 4096
#define NSPLIT 32
#define QSCALE 0.17677669529663687f  // 1/sqrt(32)
#define RMS_MUL 16.0f                // sqrt(256)
#define EPS 1e-12f

typedef __attribute__((ext_vector_type(8))) short short8;
typedef __attribute__((ext_vector_type(4))) float f32x4;

__device__ __forceinline__ ushort f2bf(float f) {
  __hip_bfloat16 h = __float2bfloat16(f);
  return *(ushort*)&h;
}
__device__ __forceinline__ float bf2f(ushort u) {
  unsigned int v = ((unsigned int)u) << 16;
  return *(float*)&v;
}
__device__ __forceinline__ void load_lds16(const void* g, void* l) {
  __builtin_amdgcn_global_load_lds((const __attribute__((address_space(1))) void*)g,
                                   (__attribute__((address_space(3))) void*)l, 16, 0, 0);
}

// ---- merged prep: blocks 0..383 -> wA; blocks 384..2431 -> x rmsnorm+transpose ----
__global__ __launch_bounds__(256) void k_prep(const float* __restrict__ wqkv,
                                              const float* __restrict__ g,
                                              const float* __restrict__ x,
                                              ushort* __restrict__ wA,
                                              ushort* __restrict__ xbf) {
  __shared__ float red[8][32];
  __shared__ float invs[32];
  int t = threadIdx.x;
  if (blockIdx.x < 384) {
    int idx = blockIdx.x * 256 + t;
    wA[idx] = f2bf(wqkv[idx] * g[idx & (C - 1)]);
    return;
  }
  int id = blockIdx.x - 384;          // 0..2047
  int g8 = t >> 5, ln = t & 31;       // channel-group, pixel
  int b = id >> 7, n0 = (id & 127) * 32;
  const float* xb = x + (size_t)b * C * N + n0 + ln;
  float v[32];
  float ss = 0.f;
  #pragma unroll
  for (int i = 0; i < 32; ++i) {
    v[i] = xb[(size_t)(g8 * 32 + i) * N];
    ss += v[i] * v[i];
  }
  red[g8][ln] = ss;
  __syncthreads();
  if (t < 32) {
    float tot = 0.f;
    #pragma unroll
    for (int j = 0; j < 8; ++j) tot += red[j][t];
    invs[t] = RMS_MUL / fmaxf(sqrtf(tot), EPS);
  }
  __syncthreads();
  float inv = invs[ln];
  ushort* dst = xbf + ((size_t)(b * N + n0 + ln)) * C + g8 * 32;
  #pragma unroll
  for (int ch = 0; ch < 4; ++ch) {
    union { ushort s[8]; uint4 q; } u;
    #pragma unroll
    for (int j = 0; j < 8; ++j) u.s[j] = f2bf(v[ch * 8 + j] * inv);
    *(uint4*)(dst + ch * 8) = u.q;
  }
}

// ---- K/V GEMM + fused context, M-split by head pair (1024 blocks) ----
__global__ __launch_bounds__(256, 4) void k_kvctx(const ushort* __restrict__ A,
                                                  const ushort* __restrict__ Bm,
                                                  float* __restrict__ ctxp) {
  const int K = 256;
  __shared__ ushort lds[16384];              // 32 KB: A[128][64]+B[128][64]; then kvt[128][128]
  ushort* Abuf = lds;
  ushort* Bbuf = lds + 8192;
  int bid = blockIdx.x;
  int work = (bid & 7) * 128 + (bid >> 3);
  int mh = work & 1, sl = (work >> 1) & 31, b = work >> 6;
  int t = threadIdx.x;
  int lane = t & 63, w = t >> 6;
  int n0 = sl * 128;
  const ushort* Bb = Bm + ((size_t)b * N + n0) * K;
  f32x4 acc[2][8] = {};
  for (int k0 = 0; k0 < K; k0 += 64) {
    #pragma unroll
    for (int i = 0; i < 4; ++i) {
      int c = w * 4 + i;
      int lr = c * 8 + (lane >> 3);
      int gr = mh * 64 + (lr & 63) + ((lr & 64) << 1);
      int col = k0 + (lane & 7) * 8;
      load_lds16(A + (size_t)gr * K + col, Abuf + c * 512);
    }
    #pragma unroll
    for (int i = 0; i < 4; ++i) {
      int c = w * 4 + i;
      int row = c * 8 + (lane >> 3);
      int col = k0 + (lane & 7) * 8;
      load_lds16(Bb + (size_t)row * K + col, Bbuf + c * 512);
    }
    __syncthreads();
    #pragma unroll
    for (int kk = 0; kk < 2; ++kk) {
      short8 af[2], bfr[8];
      #pragma unroll
      for (int m = 0; m < 2; ++m)
        af[m] = *(const short8*)&Abuf[(w * 32 + m * 16 + (lane & 15)) * 64 + kk * 32 + (lane >> 4) * 8];
      #pragma unroll
      for (int nn = 0; nn < 8; ++nn)
        bfr[nn] = *(const short8*)&Bbuf[(nn * 16 + (lane & 15)) * 64 + kk * 32 + (lane >> 4) * 8];
      #pragma unroll
      for (int m = 0; m < 2; ++m)
        #pragma unroll
        for (int nn = 0; nn < 8; ++nn)
          acc[m][nn] = __builtin_amdgcn_mfma_f32_16x16x32_bf16(af[m], bfr[nn], acc[m][nn], 0, 0, 0);
    }
    __syncthreads();
  }
  float* cbb = ctxp + (size_t)(sl * 64 + b * 4) * 1056;
  if (w < 2) {
    #pragma unroll
    for (int m = 0; m < 2; ++m)
      #pragma unroll
      for (int nn = 0; nn < 8; ++nn)
        #pragma unroll
        for (int j = 0; j < 4; ++j) acc[m][nn][j] = __expf(acc[m][nn][j]);
    #pragma unroll
    for (int m = 0; m < 2; ++m)
      #pragma unroll
      for (int j = 0; j < 4; ++j) {
        float s = 0.f;
        #pragma unroll
        for (int nn = 0; nn < 8; ++nn) s += acc[m][nn][j];
        s += __shfl_xor(s, 1); s += __shfl_xor(s, 2);
        s += __shfl_xor(s, 4); s += __shfl_xor(s, 8);
        if ((lane & 15) == 0) {
          int lr = w * 32 + m * 16 + (lane >> 4) * 4 + j;
          int h = mh * 2 + (lr >> 5);
          cbb[(size_t)h * 1056 + 1024 + (lr & 31)] = s;
        }
      }
  }
  #pragma unroll
  for (int m = 0; m < 2; ++m)
    #pragma unroll
    for (int nn = 0; nn < 8; ++nn) {
      int lr0 = w * 32 + m * 16 + (lane >> 4) * 4;
      int n = nn * 16 + (lane & 15);
      #pragma unroll
      for (int j = 0; j < 4; ++j) {
        int lr = lr0 + j;
        lds[(lr * 128 + n) ^ ((lr & 7) << 3)] = f2bf(acc[m][nn][j]);
      }
    }
  __syncthreads();
  int hl = w >> 1, eh = w & 1;
  f32x4 cacc[2] = {};
  #pragma unroll
  for (int kk = 0; kk < 4; ++kk) {
    short8 af2[2], bv;
    #pragma unroll
    for (int m = 0; m < 2; ++m) {
      int lrk = hl * 32 + m * 16 + (lane & 15);
      af2[m] = *(const short8*)&lds[(lrk * 128 + kk * 32 + (lane >> 4) * 8) ^ ((lrk & 7) << 3)];
    }
    int lrv = 64 + hl * 32 + eh * 16 + (lane & 15);
    bv = *(const short8*)&lds[(lrv * 128 + kk * 32 + (lane >> 4) * 8) ^ ((lrv & 7) << 3)];
    #pragma unroll
    for (int m = 0; m < 2; ++m)
      cacc[m] = __builtin_amdgcn_mfma_f32_16x16x32_bf16(af2[m], bv, cacc[m], 0, 0, 0);
  }
  int hg = mh * 2 + hl;
  float* cb = ctxp + (size_t)(sl * 64 + b * 4 + hg) * 1056;
  #pragma unroll
  for (int m = 0; m < 2; ++m)
    #pragma unroll
    for (int j = 0; j < 4; ++j) {
      int d = m * 16 + (lane >> 4) * 4 + j;
      int e = eh * 16 + (lane & 15);
      cb[d * 32 + e] = cacc[m][j];
    }
}

// ---- reduce partials + normalize + Weff build (64 blocks) ----
__global__ __launch_bounds__(256) void k_redweff(const float* __restrict__ ctxp,
                                                 const float* __restrict__ wout,
                                                 ushort* __restrict__ Weff) {
  __shared__ float ctxn[D][D + 1];
  __shared__ float ksum[D];
  int bh = blockIdx.x;
  int b = bh >> 2, h = bh & 3;
  int t = threadIdx.x;
  int d = t >> 3, e0 = (t & 7) * 4;
  float vs[4] = {0.f, 0.f, 0.f, 0.f};
  float ks = 0.f;
  for (int s = 0; s < NSPLIT; ++s) {
    const float* cb = ctxp + (size_t)(s * 64 + bh) * 1056;
    f32x4 v = *(const f32x4*)(cb + d * 32 + e0);
    vs[0] += v[0]; vs[1] += v[1]; vs[2] += v[2]; vs[3] += v[3];
    if (t < 32) ks += cb[1024 + t];
  }
  if (t < 32) ksum[t] = ks;
  __syncthreads();
  float rk = 1.f / ksum[d];
  #pragma unroll
  for (int j = 0; j < 4; ++j) ctxn[d][e0 + j] = vs[j] * rk;
  __syncthreads();
  float wrow[D];
  #pragma unroll
  for (int e = 0; e < D; ++e) wrow[e] = wout[t * HID + h * D + e];
  ushort* wb = Weff + ((size_t)(b * C + t)) * HID + h * D;
  #pragma unroll
  for (int g = 0; g < 4; ++g) {
    union { ushort s[8]; uint4 v; } u;
    #pragma unroll
    for (int dj = 0; dj < 8; ++dj) {
      int dd = g * 8 + dj;
      float a = 0.f;
      #pragma unroll
      for (int e = 0; e < D; ++e) a += wrow[e] * ctxn[dd][e];
      u.s[dj] = f2bf(a);
    }
    *(uint4*)(wb + g * 8) = u.v;
  }
}

// ---- fused q-GEMM + softmax + (Weff x qT) + bias + rmsnorm (1024 blocks, N=64) ----
__global__ __launch_bounds__(256, 4) void k_qout(const ushort* __restrict__ A,
                                                 const ushort* __restrict__ Bm,
                                                 const ushort* __restrict__ WeffG,
                                                 const float* __restrict__ bias,
                                                 const float* __restrict__ g,
                                                 float* __restrict__ outp) {
  const int K = 256;
  __shared__ ushort lds[16384];       // 32 KB
  ushort* Abuf = lds;                 // ph1 A [128][64]
  ushort* Bbuf = lds + 8192;          // ph1 B [64][64]
  ushort* qlds = lds + 8192;          // q [64 n][128 d] (after ph1)
  ushort* A2buf = lds;                // ph2 A [256][32]
  int bid = blockIdx.x;
  int work = (bid & 7) * 128 + (bid >> 3);
  int xt = work & 63, b = work >> 6;
  int t = threadIdx.x;
  int lane = t & 63, w = t >> 6;
  int n0 = xt * 64;
  const ushort* Bb = Bm + ((size_t)b * N + n0) * K;
  // ---- phase 1: q GEMM (128 d x 64 n, K=256) + per-head softmax + qlds dump ----
  {
    f32x4 acc[2][4] = {};
    for (int k0 = 0; k0 < K; k0 += 64) {
      #pragma unroll
      for (int i = 0; i < 4; ++i) {
        int c = w * 4 + i;
        int row = c * 8 + (lane >> 3);
        int col = k0 + (lane & 7) * 8;
        load_lds16(A + (size_t)row * K + col, Abuf + c * 512);
      }
      #pragma unroll
      for (int i = 0; i < 2; ++i) {
        int c = w * 2 + i;
        int row = c * 8 + (lane >> 3);
        int col = k0 + (lane & 7) * 8;
        load_lds16(Bb + (size_t)row * K + col, Bbuf + c * 512);
      }
      __syncthreads();
      #pragma unroll
      for (int kk = 0; kk < 2; ++kk) {
        short8 af[2], bfr[4];
        #pragma unroll
        for (int m = 0; m < 2; ++m)
          af[m] = *(const short8*)&Abuf[(w * 32 + m * 16 + (lane & 15)) * 64 + kk * 32 + (lane >> 4) * 8];
        #pragma unroll
        for (int nn = 0; nn < 4; ++nn)
          bfr[nn] = *(const short8*)&Bbuf[(nn * 16 + (lane & 15)) * 64 + kk * 32 + (lane >> 4) * 8];
        #pragma unroll
        for (int m = 0; m < 2; ++m)
          #pragma unroll
          for (int nn = 0; nn < 4; ++nn)
            acc[m][nn] = __builtin_amdgcn_mfma_f32_16x16x32_bf16(af[m], bfr[nn], acc[m][nn], 0, 0, 0);
      }
      __syncthreads();
    }
    #pragma unroll
    for (int nn = 0; nn < 4; ++nn) {
      float pm = -1e30f;
      #pragma unroll
      for (int m = 0; m < 2; ++m)
        #pragma unroll
        for (int j = 0; j < 4; ++j) pm = fmaxf(pm, acc[m][nn][j]);
      pm = fmaxf(pm, __shfl_xor(pm, 16));
      pm = fmaxf(pm, __shfl_xor(pm, 32));
      float e[2][4], ps = 0.f;
      #pragma unroll
      for (int m = 0; m < 2; ++m)
        #pragma unroll
        for (int j = 0; j < 4; ++j) {
          e[m][j] = __expf(acc[m][nn][j] - pm);
          ps += e[m][j];
        }
      ps += __shfl_xor(ps, 16);
      ps += __shfl_xor(ps, 32);
      float rs = QSCALE / ps;
      #pragma unroll
      for (int m = 0; m < 2; ++m)
        #pragma unroll
        for (int j = 0; j < 4; ++j) acc[m][nn][j] = e[m][j] * rs;
    }
    #pragma unroll
    for (int m = 0; m < 2; ++m)
      #pragma unroll
      for (int nn = 0; nn < 4; ++nn) {
        int d0 = w * 32 + m * 16 + (lane >> 4) * 4;
        int n = nn * 16 + (lane & 15);
        union { ushort us[4]; uint2 v; } u;
        #pragma unroll
        for (int j = 0; j < 4; ++j) u.us[j] = f2bf(acc[m][nn][j]);
        *(uint2*)&qlds[(n * 128 + d0) ^ ((n & 7) << 3)] = u.v;
      }
  }
  __syncthreads();
  // ---- phase 2: out = Weff[b] (256x128) x qT (64 n), BK=32 ----
  const ushort* Aw = WeffG + (size_t)b * C * HID;
  f32x4 acc2[4][4] = {};
  for (int k0 = 0; k0 < HID; k0 += 32) {
    #pragma unroll
    for (int i = 0; i < 4; ++i) {
      int c = w * 4 + i;
      int row = c * 16 + (lane >> 2);
      int col = k0 + (lane & 3) * 8;
      load_lds16(Aw + (size_t)row * HID + col, A2buf + c * 512);
    }
    __syncthreads();
    short8 af[4], bfr[4];
    #pragma unroll
    for (int m = 0; m < 4; ++m)
      af[m] = *(const short8*)&A2buf[(w * 64 + m * 16 + (lane & 15)) * 32 + (lane >> 4) * 8];
    #pragma unroll
    for (int nn = 0; nn < 4; ++nn) {
      int n = nn * 16 + (lane & 15);
      bfr[nn] = *(const short8*)&qlds[(n * 128 + k0 + (lane >> 4) * 8) ^ ((n & 7) << 3)];
    }
    #pragma unroll
    for (int m = 0; m < 4; ++m)
      #pragma unroll
      for (int nn = 0; nn < 4; ++nn)
        acc2[m][nn] = __builtin_amdgcn_mfma_f32_16x16x32_bf16(af[m], bfr[nn], acc2[m][nn], 0, 0, 0);
    __syncthreads();
  }
  // ---- epilogue: bias + per-column rmsnorm + write ----
  float* ssred = (float*)lds;
  #pragma unroll
  for (int m = 0; m < 4; ++m)
    #pragma unroll
    for (int j = 0; j < 4; ++j) {
      int row = w * 64 + m * 16 + (lane >> 4) * 4 + j;
      float bv = bias[row];
      #pragma unroll
      for (int nn = 0; nn < 4; ++nn) acc2[m][nn][j] += bv;
    }
  float ssp[4];
  #pragma unroll
  for (int nn = 0; nn < 4; ++nn) {
    float s = 0.f;
    #pragma unroll
    for (int m = 0; m < 4; ++m)
      #pragma unroll
      for (int j = 0; j < 4; ++j) s += acc2[m][nn][j] * acc2[m][nn][j];
    s += __shfl_xor(s, 16);
    s += __shfl_xor(s, 32);
    ssp[nn] = s;
  }
  if ((lane >> 4) == 0) {
    #pragma unroll
    for (int nn = 0; nn < 4; ++nn) ssred[w * 64 + nn * 16 + (lane & 15)] = ssp[nn];
  }
  __syncthreads();
  float inv[4];
  #pragma unroll
  for (int nn = 0; nn < 4; ++nn) {
    int col = nn * 16 + (lane & 15);
    float tot = ssred[col] + ssred[64 + col] + ssred[128 + col] + ssred[192 + col];
    inv[nn] = RMS_MUL / fmaxf(sqrtf(tot), EPS);
  }
  float* Cb = outp + (size_t)b * C * N + n0;
  #pragma unroll
  for (int m = 0; m < 4; ++m)
    #pragma unroll
    for (int j = 0; j < 4; ++j) {
      int row = w * 64 + m * 16 + (lane >> 4) * 4 + j;
      float gm = g[row];
      #pragma unroll
      for (int nn = 0; nn < 4; ++nn) {
        int col = nn * 16 + (lane & 15);
        Cb[(size_t)row * N + col] = acc2[m][nn][j] * inv[nn] * gm;
      }
    }
}

extern "C" void kernel_launch(void* const* d_in, const int* in_sizes, int n_in,
                              void* d_out, int out_size, void* d_ws, size_t ws_size,
                              hipStream_t stream) {
  const float* x    = (const float*)d_in[0];
  const float* gn   = (const float*)d_in[1];
  const float* wqkv = (const float*)d_in[2];
  const float* wout = (const float*)d_in[3];
  const float* bout = (const float*)d_in[4];
  const float* gout = (const float*)d_in[5];
  float* out = (float*)d_out;
  float* ws  = (float*)d_ws;

  ushort* xbf  = (ushort*)ws;                    // 32 MB [b][n][c]
  float*  ctxp = ws + 8388608;                   // 8.65 MB
  ushort* Weff = (ushort*)(ws + 10551296);       // 1 MB
  ushort* wA   = (ushort*)(ws + 10813440);       // 192 KB

  k_prep   <<<2432, 256, 0, stream>>>(wqkv, gn, x, wA, xbf);
  k_kvctx  <<<1024, 256, 0, stream>>>(wA + 128 * 256, xbf, ctxp);
  k_redweff<<<64, 256, 0, stream>>>(ctxp, wout, Weff);
  k_qout   <<<1024, 256, 0, stream>>>(wA, xbf, Weff, bout, gout, out);
}

// Round 13
// 85.088 us; speedup vs baseline: 1.4780x; 1.0143x over previous
//
// R13: R11 structure (4 kernels) + minimum-2-phase prefetch (BK=32 double-
//      buffered staging, counted-drain raw barrier) in kvctx and qout ph1.
//      prep/redweff/qout-ph2 byte-identical to R11.
#include <hip/hip_runtime.h>
#include <hip/hip_bf16.h>
#include <math.h>

#define B 16
#define C 256
#define H 4
#define D 32
#define HID 128
#define O3 384
#define N 4096
#define NSPLIT 32
#define QSCALE 0.17677669529663687f  // 1/sqrt(32)
#define RMS_MUL 16.0f                // sqrt(256)
#define EPS 1e-12f

typedef __attribute__((ext_vector_type(8))) short short8;
typedef __attribute__((ext_vector_type(4))) float f32x4;

#define VM0_BARRIER() asm volatile("s_waitcnt vmcnt(0)\ns_barrier" ::: "memory")

__device__ __forceinline__ ushort f2bf(float f) {
  __hip_bfloat16 h = __float2bfloat16(f);
  return *(ushort*)&h;
}
__device__ __forceinline__ void load_lds16(const void* g, void* l) {
  __builtin_amdgcn_global_load_lds((const __attribute__((address_space(1))) void*)g,
                                   (__attribute__((address_space(3))) void*)l, 16, 0, 0);
}

// ---- merged prep: blocks 0..383 -> wA; blocks 384..2431 -> x rmsnorm+transpose ----
__global__ __launch_bounds__(256) void k_prep(const float* __restrict__ wqkv,
                                              const float* __restrict__ g,
                                              const float* __restrict__ x,
                                              ushort* __restrict__ wA,
                                              ushort* __restrict__ xbf) {
  __shared__ float red[8][32];
  __shared__ float invs[32];
  int t = threadIdx.x;
  if (blockIdx.x < 384) {
    int idx = blockIdx.x * 256 + t;
    wA[idx] = f2bf(wqkv[idx] * g[idx & (C - 1)]);
    return;
  }
  int id = blockIdx.x - 384;
  int g8 = t >> 5, ln = t & 31;
  int b = id >> 7, n0 = (id & 127) * 32;
  const float* xb = x + (size_t)b * C * N + n0 + ln;
  float v[32];
  float ss = 0.f;
  #pragma unroll
  for (int i = 0; i < 32; ++i) {
    v[i] = xb[(size_t)(g8 * 32 + i) * N];
    ss += v[i] * v[i];
  }
  red[g8][ln] = ss;
  __syncthreads();
  if (t < 32) {
    float tot = 0.f;
    #pragma unroll
    for (int j = 0; j < 8; ++j) tot += red[j][t];
    invs[t] = RMS_MUL / fmaxf(sqrtf(tot), EPS);
  }
  __syncthreads();
  float inv = invs[ln];
  ushort* dst = xbf + ((size_t)(b * N + n0 + ln)) * C + g8 * 32;
  #pragma unroll
  for (int ch = 0; ch < 4; ++ch) {
    union { ushort s[8]; uint4 q; } u;
    #pragma unroll
    for (int j = 0; j < 8; ++j) u.s[j] = f2bf(v[ch * 8 + j] * inv);
    *(uint4*)(dst + ch * 8) = u.q;
  }
}

// ---- K/V GEMM + fused context, BK=32 dbuf prefetch (1024 blocks) ----
__global__ __launch_bounds__(256, 4) void k_kvctx(const ushort* __restrict__ A,
                                                  const ushort* __restrict__ Bm,
                                                  float* __restrict__ ctxp) {
  const int K = 256;
  __shared__ ushort lds[16384];   // A dbuf [0,8192) us; B dbuf [8192,16384); then kvt
  int bid = blockIdx.x;
  int work = (bid & 7) * 128 + (bid >> 3);
  int mh = work & 1, sl = (work >> 1) & 31, b = work >> 6;
  int t = threadIdx.x;
  int lane = t & 63, w = t >> 6;
  int n0 = sl * 128;
  const ushort* Bb = Bm + ((size_t)b * N + n0) * K;
  f32x4 acc[2][8] = {};

  auto stage = [&](int buf, int k0) {
    #pragma unroll
    for (int i = 0; i < 2; ++i) {
      int c = w * 2 + i;                     // 8 chunks, 16 rows each
      int lr = c * 16 + (lane >> 2);         // local row 0..127
      int gr = mh * 64 + (lr & 63) + ((lr & 64) << 1);
      int col = k0 + (lane & 3) * 8;
      load_lds16(A + (size_t)gr * K + col, lds + buf * 4096 + c * 512);
    }
    #pragma unroll
    for (int i = 0; i < 2; ++i) {
      int c = w * 2 + i;
      int row = c * 16 + (lane >> 2);
      int col = k0 + (lane & 3) * 8;
      load_lds16(Bb + (size_t)row * K + col, lds + 8192 + buf * 4096 + c * 512);
    }
  };

  stage(0, 0);
  VM0_BARRIER();
  #pragma unroll
  for (int ki = 0; ki < 8; ++ki) {
    int cur = ki & 1;
    if (ki < 7) stage(cur ^ 1, (ki + 1) * 32);
    const ushort* Ar = lds + cur * 4096;
    const ushort* Br = lds + 8192 + cur * 4096;
    short8 af[2], bfr[8];
    #pragma unroll
    for (int m = 0; m < 2; ++m)
      af[m] = *(const short8*)&Ar[(w * 32 + m * 16 + (lane & 15)) * 32 + (lane >> 4) * 8];
    #pragma unroll
    for (int nn = 0; nn < 8; ++nn)
      bfr[nn] = *(const short8*)&Br[(nn * 16 + (lane & 15)) * 32 + (lane >> 4) * 8];
    #pragma unroll
    for (int m = 0; m < 2; ++m)
      #pragma unroll
      for (int nn = 0; nn < 8; ++nn)
        acc[m][nn] = __builtin_amdgcn_mfma_f32_16x16x32_bf16(af[m], bfr[nn], acc[m][nn], 0, 0, 0);
    VM0_BARRIER();
  }

  float* cbb = ctxp + (size_t)(sl * 64 + b * 4) * 1056;
  if (w < 2) {
    #pragma unroll
    for (int m = 0; m < 2; ++m)
      #pragma unroll
      for (int nn = 0; nn < 8; ++nn)
        #pragma unroll
        for (int j = 0; j < 4; ++j) acc[m][nn][j] = __expf(acc[m][nn][j]);
    #pragma unroll
    for (int m = 0; m < 2; ++m)
      #pragma unroll
      for (int j = 0; j < 4; ++j) {
        float s = 0.f;
        #pragma unroll
        for (int nn = 0; nn < 8; ++nn) s += acc[m][nn][j];
        s += __shfl_xor(s, 1); s += __shfl_xor(s, 2);
        s += __shfl_xor(s, 4); s += __shfl_xor(s, 8);
        if ((lane & 15) == 0) {
          int lr = w * 32 + m * 16 + (lane >> 4) * 4 + j;
          int h = mh * 2 + (lr >> 5);
          cbb[(size_t)h * 1056 + 1024 + (lr & 31)] = s;
        }
      }
  }
  #pragma unroll
  for (int m = 0; m < 2; ++m)
    #pragma unroll
    for (int nn = 0; nn < 8; ++nn) {
      int lr0 = w * 32 + m * 16 + (lane >> 4) * 4;
      int n = nn * 16 + (lane & 15);
      #pragma unroll
      for (int j = 0; j < 4; ++j) {
        int lr = lr0 + j;
        lds[(lr * 128 + n) ^ ((lr & 7) << 3)] = f2bf(acc[m][nn][j]);
      }
    }
  __syncthreads();
  int hl = w >> 1, eh = w & 1;
  f32x4 cacc[2] = {};
  #pragma unroll
  for (int kk = 0; kk < 4; ++kk) {
    short8 af2[2], bv;
    #pragma unroll
    for (int m = 0; m < 2; ++m) {
      int lrk = hl * 32 + m * 16 + (lane & 15);
      af2[m] = *(const short8*)&lds[(lrk * 128 + kk * 32 + (lane >> 4) * 8) ^ ((lrk & 7) << 3)];
    }
    int lrv = 64 + hl * 32 + eh * 16 + (lane & 15);
    bv = *(const short8*)&lds[(lrv * 128 + kk * 32 + (lane >> 4) * 8) ^ ((lrv & 7) << 3)];
    #pragma unroll
    for (int m = 0; m < 2; ++m)
      cacc[m] = __builtin_amdgcn_mfma_f32_16x16x32_bf16(af2[m], bv, cacc[m], 0, 0, 0);
  }
  int hg = mh * 2 + hl;
  float* cb = ctxp + (size_t)(sl * 64 + b * 4 + hg) * 1056;
  #pragma unroll
  for (int m = 0; m < 2; ++m)
    #pragma unroll
    for (int j = 0; j < 4; ++j) {
      int d = m * 16 + (lane >> 4) * 4 + j;
      int e = eh * 16 + (lane & 15);
      cb[d * 32 + e] = cacc[m][j];
    }
}

// ---- reduce partials + normalize + Weff build (64 blocks) ----
__global__ __launch_bounds__(256) void k_redweff(const float* __restrict__ ctxp,
                                                 const float* __restrict__ wout,
                                                 ushort* __restrict__ Weff) {
  __shared__ float ctxn[D][D + 1];
  __shared__ float ksum[D];
  int bh = blockIdx.x;
  int b = bh >> 2, h = bh & 3;
  int t = threadIdx.x;
  int d = t >> 3, e0 = (t & 7) * 4;
  float vs[4] = {0.f, 0.f, 0.f, 0.f};
  float ks = 0.f;
  for (int s = 0; s < NSPLIT; ++s) {
    const float* cb = ctxp + (size_t)(s * 64 + bh) * 1056;
    f32x4 v = *(const f32x4*)(cb + d * 32 + e0);
    vs[0] += v[0]; vs[1] += v[1]; vs[2] += v[2]; vs[3] += v[3];
    if (t < 32) ks += cb[1024 + t];
  }
  if (t < 32) ksum[t] = ks;
  __syncthreads();
  float rk = 1.f / ksum[d];
  #pragma unroll
  for (int j = 0; j < 4; ++j) ctxn[d][e0 + j] = vs[j] * rk;
  __syncthreads();
  float wrow[D];
  #pragma unroll
  for (int e = 0; e < D; ++e) wrow[e] = wout[t * HID + h * D + e];
  ushort* wb = Weff + ((size_t)(b * C + t)) * HID + h * D;
  #pragma unroll
  for (int g = 0; g < 4; ++g) {
    union { ushort s[8]; uint4 v; } u;
    #pragma unroll
    for (int dj = 0; dj < 8; ++dj) {
      int dd = g * 8 + dj;
      float a = 0.f;
      #pragma unroll
      for (int e = 0; e < D; ++e) a += wrow[e] * ctxn[dd][e];
      u.s[dj] = f2bf(a);
    }
    *(uint4*)(wb + g * 8) = u.v;
  }
}

// ---- fused q-GEMM (BK=32 dbuf prefetch) + softmax + (Weff x qT) + rmsnorm ----
__global__ __launch_bounds__(256, 4) void k_qout(const ushort* __restrict__ A,
                                                 const ushort* __restrict__ Bm,
                                                 const ushort* __restrict__ WeffG,
                                                 const float* __restrict__ bias,
                                                 const float* __restrict__ g,
                                                 float* __restrict__ outp) {
  const int K = 256;
  __shared__ ushort lds[16384];
  // ph1: A dbuf [0,4096),(4096,8192); B dbuf [8192,10240),(10240,12288)
  // qlds [64 n][128 d] at [8192,16384) (after ph1); ph2 A2buf at [0,8192)
  ushort* qlds = lds + 8192;
  int bid = blockIdx.x;
  int work = (bid & 7) * 128 + (bid >> 3);
  int xt = work & 63, b = work >> 6;
  int t = threadIdx.x;
  int lane = t & 63, w = t >> 6;
  int n0 = xt * 64;
  const ushort* Bb = Bm + ((size_t)b * N + n0) * K;
  // ---- phase 1: q GEMM (128 d x 64 n, BK=32 prefetch) + softmax + dump ----
  {
    auto stage1 = [&](int buf, int k0) {
      #pragma unroll
      for (int i = 0; i < 2; ++i) {
        int c = w * 2 + i;                   // A: 8 chunks
        int row = c * 16 + (lane >> 2);
        int col = k0 + (lane & 3) * 8;
        load_lds16(A + (size_t)row * K + col, lds + buf * 4096 + c * 512);
      }
      {
        int c = w;                           // B: 4 chunks
        int row = c * 16 + (lane >> 2);
        int col = k0 + (lane & 3) * 8;
        load_lds16(Bb + (size_t)row * K + col, lds + 8192 + buf * 2048 + c * 512);
      }
    };
    f32x4 acc[2][4] = {};
    stage1(0, 0);
    VM0_BARRIER();
    #pragma unroll
    for (int ki = 0; ki < 8; ++ki) {
      int cur = ki & 1;
      if (ki < 7) stage1(cur ^ 1, (ki + 1) * 32);
      const ushort* Ar = lds + cur * 4096;
      const ushort* Br = lds + 8192 + cur * 2048;
      short8 af[2], bfr[4];
      #pragma unroll
      for (int m = 0; m < 2; ++m)
        af[m] = *(const short8*)&Ar[(w * 32 + m * 16 + (lane & 15)) * 32 + (lane >> 4) * 8];
      #pragma unroll
      for (int nn = 0; nn < 4; ++nn)
        bfr[nn] = *(const short8*)&Br[(nn * 16 + (lane & 15)) * 32 + (lane >> 4) * 8];
      #pragma unroll
      for (int m = 0; m < 2; ++m)
        #pragma unroll
        for (int nn = 0; nn < 4; ++nn)
          acc[m][nn] = __builtin_amdgcn_mfma_f32_16x16x32_bf16(af[m], bfr[nn], acc[m][nn], 0, 0, 0);
      VM0_BARRIER();
    }
    // per-head softmax (wave w = head w, rows w*32..+32) per column
    #pragma unroll
    for (int nn = 0; nn < 4; ++nn) {
      float pm = -1e30f;
      #pragma unroll
      for (int m = 0; m < 2; ++m)
        #pragma unroll
        for (int j = 0; j < 4; ++j) pm = fmaxf(pm, acc[m][nn][j]);
      pm = fmaxf(pm, __shfl_xor(pm, 16));
      pm = fmaxf(pm, __shfl_xor(pm, 32));
      float e[2][4], ps = 0.f;
      #pragma unroll
      for (int m = 0; m < 2; ++m)
        #pragma unroll
        for (int j = 0; j < 4; ++j) {
          e[m][j] = __expf(acc[m][nn][j] - pm);
          ps += e[m][j];
        }
      ps += __shfl_xor(ps, 16);
      ps += __shfl_xor(ps, 32);
      float rs = QSCALE / ps;
      #pragma unroll
      for (int m = 0; m < 2; ++m)
        #pragma unroll
        for (int j = 0; j < 4; ++j) acc[m][nn][j] = e[m][j] * rs;
    }
    // dump q to qlds[n][d] (swizzled); staging dead after final barrier
    #pragma unroll
    for (int m = 0; m < 2; ++m)
      #pragma unroll
      for (int nn = 0; nn < 4; ++nn) {
        int d0 = w * 32 + m * 16 + (lane >> 4) * 4;
        int n = nn * 16 + (lane & 15);
        union { ushort us[4]; uint2 v; } u;
        #pragma unroll
        for (int j = 0; j < 4; ++j) u.us[j] = f2bf(acc[m][nn][j]);
        *(uint2*)&qlds[(n * 128 + d0) ^ ((n & 7) << 3)] = u.v;
      }
  }
  __syncthreads();
  // ---- phase 2: out = Weff[b] (256x128) x qT (64 n), BK=32 (as R11) ----
  const ushort* Aw = WeffG + (size_t)b * C * HID;
  ushort* A2buf = lds;
  f32x4 acc2[4][4] = {};
  for (int k0 = 0; k0 < HID; k0 += 32) {
    #pragma unroll
    for (int i = 0; i < 4; ++i) {
      int c = w * 4 + i;
      int row = c * 16 + (lane >> 2);
      int col = k0 + (lane & 3) * 8;
      load_lds16(Aw + (size_t)row * HID + col, A2buf + c * 512);
    }
    __syncthreads();
    short8 af[4], bfr[4];
    #pragma unroll
    for (int m = 0; m < 4; ++m)
      af[m] = *(const short8*)&A2buf[(w * 64 + m * 16 + (lane & 15)) * 32 + (lane >> 4) * 8];
    #pragma unroll
    for (int nn = 0; nn < 4; ++nn) {
      int n = nn * 16 + (lane & 15);
      bfr[nn] = *(const short8*)&qlds[(n * 128 + k0 + (lane >> 4) * 8) ^ ((n & 7) << 3)];
    }
    #pragma unroll
    for (int m = 0; m < 4; ++m)
      #pragma unroll
      for (int nn = 0; nn < 4; ++nn)
        acc2[m][nn] = __builtin_amdgcn_mfma_f32_16x16x32_bf16(af[m], bfr[nn], acc2[m][nn], 0, 0, 0);
    __syncthreads();
  }
  // ---- epilogue: bias + per-column rmsnorm + write ----
  float* ssred = (float*)lds;
  #pragma unroll
  for (int m = 0; m < 4; ++m)
    #pragma unroll
    for (int j = 0; j < 4; ++j) {
      int row = w * 64 + m * 16 + (lane >> 4) * 4 + j;
      float bv = bias[row];
      #pragma unroll
      for (int nn = 0; nn < 4; ++nn) acc2[m][nn][j] += bv;
    }
  float ssp[4];
  #pragma unroll
  for (int nn = 0; nn < 4; ++nn) {
    float s = 0.f;
    #pragma unroll
    for (int m = 0; m < 4; ++m)
      #pragma unroll
      for (int j = 0; j < 4; ++j) s += acc2[m][nn][j] * acc2[m][nn][j];
    s += __shfl_xor(s, 16);
    s += __shfl_xor(s, 32);
    ssp[nn] = s;
  }
  if ((lane >> 4) == 0) {
    #pragma unroll
    for (int nn = 0; nn < 4; ++nn) ssred[w * 64 + nn * 16 + (lane & 15)] = ssp[nn];
  }
  __syncthreads();
  float inv[4];
  #pragma unroll
  for (int nn = 0; nn < 4; ++nn) {
    int col = nn * 16 + (lane & 15);
    float tot = ssred[col] + ssred[64 + col] + ssred[128 + col] + ssred[192 + col];
    inv[nn] = RMS_MUL / fmaxf(sqrtf(tot), EPS);
  }
  float* Cb = outp + (size_t)b * C * N + n0;
  #pragma unroll
  for (int m = 0; m < 4; ++m)
    #pragma unroll
    for (int j = 0; j < 4; ++j) {
      int row = w * 64 + m * 16 + (lane >> 4) * 4 + j;
      float gm = g[row];
      #pragma unroll
      for (int nn = 0; nn < 4; ++nn) {
        int col = nn * 16 + (lane & 15);
        Cb[(size_t)row * N + col] = acc2[m][nn][j] * inv[nn] * gm;
      }
    }
}

extern "C" void kernel_launch(void* const* d_in, const int* in_sizes, int n_in,
                              void* d_out, int out_size, void* d_ws, size_t ws_size,
                              hipStream_t stream) {
  const float* x    = (const float*)d_in[0];
  const float* gn   = (const float*)d_in[1];
  const float* wqkv = (const float*)d_in[2];
  const float* wout = (const float*)d_in[3];
  const float* bout = (const float*)d_in[4];
  const float* gout = (const float*)d_in[5];
  float* out = (float*)d_out;
  float* ws  = (float*)d_ws;

  ushort* xbf  = (ushort*)ws;                    // 32 MB [b][n][c]
  float*  ctxp = ws + 8388608;                   // 8.65 MB
  ushort* Weff = (ushort*)(ws + 10551296);       // 1 MB
  ushort* wA   = (ushort*)(ws + 10813440);       // 192 KB

  k_prep   <<<2432, 256, 0, stream>>>(wqkv, gn, x, wA, xbf);
  k_kvctx  <<<1024, 256, 0, stream>>>(wA + 128 * 256, xbf, ctxp);
  k_redweff<<<64, 256, 0, stream>>>(ctxp, wout, Weff);
  k_qout   <<<1024, 256, 0, stream>>>(wA, xbf, Weff, bout, gout, out);
}